// Round 1
// baseline (964.593 us; speedup 1.0000x reference)
//
#include <hip/hip_runtime.h>
#include <hip/hip_bf16.h>
#include <hip/hip_fp16.h>

#define GN 100000
#define GE 600000
#define SCAN_NBLK 98   // ceil(GN / 1024)
#define ALD 132        // fp32 LDS leading dim: 128 + 4
#define CSR_PAD 256    // zeroed tail so pipelined gather never reads junk

typedef __bf16    bf16x8 __attribute__((ext_vector_type(8)));
typedef __bf16    bf16x4 __attribute__((ext_vector_type(4)));
typedef _Float16  f16x8  __attribute__((ext_vector_type(8)));
typedef float     f32x4  __attribute__((ext_vector_type(4)));

// ---------------------------------------------------------------------------
// Weight pre-conversion: fp32 -> (hi, lo) bf16 planes, ONCE per launch.
// [0,16384) W_in[128,128]; [16384,65536) W_convs[3][128][128];
// [65536,98304) W_out[64,512]. All row-major [OC, K].
// ---------------------------------------------------------------------------
__global__ __launch_bounds__(256) void convert_w(
    const float* __restrict__ Win, const float* __restrict__ Wc,
    const float* __restrict__ Wout,
    __bf16* __restrict__ hi, __bf16* __restrict__ lo)
{
    const int i = blockIdx.x * 256 + threadIdx.x;
    if (i >= 98304) return;
    float v;
    if (i < 16384)      v = Win[i];
    else if (i < 65536) v = Wc[i - 16384];
    else                v = Wout[i - 65536];
    const __bf16 h = (__bf16)v;
    hi[i] = h;
    lo[i] = (__bf16)(v - (float)h);
}

// ---------------------------------------------------------------------------
// 2-deep software-pipelined 8-row fp16 gather (one wave owns 8 rows).
// Pipeline state per row: cursor pc8 walks csr 2 entries ahead; row loads are
// double-buffered (tA consumed while tB + next addresses in flight), so every
// wait leaves ~16 loads outstanding instead of 0. csr is padded with CSR_PAD
// zeroed ints -> over-reads yield node 0 (valid address, value masked by
// k<deg), so no per-iteration clamps are needed.
// Ends with __syncthreads() + accumulate into Acc rows [wave*8, wave*8+8).
// ---------------------------------------------------------------------------
__device__ __forceinline__ void gather8_f16(
    const uint* __restrict__ Hw,
    const int* __restrict__ row_start,
    const int* __restrict__ deg,
    const int* __restrict__ csr,
    const int row0, const int wave, const int lane,
    float* __restrict__ Acc)
{
    float2 acc8[8];
    int pc8[8], dg8[8];
    int maxd = 0;
#pragma unroll
    for (int r = 0; r < 8; ++r) {
        acc8[r] = make_float2(0.f, 0.f);
        const int v = row0 + wave * 8 + r;
        pc8[r] = (v < GN) ? row_start[v] : 0;
        dg8[r] = (v < GN) ? deg[v] : 0;
        maxd = max(maxd, dg8[r]);
    }

    // prologue: addresses for k=0 (sA) and k=1 (sB); rows for k=0 (tA)
    int sA[8], sB[8];
#pragma unroll
    for (int r = 0; r < 8; ++r) sA[r] = csr[pc8[r]];
#pragma unroll
    for (int r = 0; r < 8; ++r) sB[r] = csr[pc8[r] + 1];
#pragma unroll
    for (int r = 0; r < 8; ++r) pc8[r] += 2;
    uint tA[8];
#pragma unroll
    for (int r = 0; r < 8; ++r) tA[r] = Hw[(size_t)sA[r] * 64 + lane];

    for (int k = 0; k < maxd; k += 2) {
        // issue addresses for k+2, rows for k+1; consume rows of k
        int sN[8];
#pragma unroll
        for (int r = 0; r < 8; ++r) sN[r] = csr[pc8[r]];
        uint tB[8];
#pragma unroll
        for (int r = 0; r < 8; ++r) tB[r] = Hw[(size_t)sB[r] * 64 + lane];
#pragma unroll
        for (int r = 0; r < 8; ++r) {
            union { uint u; _Float16 h[2]; } cv;
            cv.u = (k < dg8[r]) ? tA[r] : 0u;
            acc8[r].x += (float)cv.h[0];
            acc8[r].y += (float)cv.h[1];
        }
        // issue addresses for k+3, rows for k+2; consume rows of k+1
        int sM[8];
#pragma unroll
        for (int r = 0; r < 8; ++r) sM[r] = csr[pc8[r] + 1];
#pragma unroll
        for (int r = 0; r < 8; ++r) pc8[r] += 2;
#pragma unroll
        for (int r = 0; r < 8; ++r) tA[r] = Hw[(size_t)sN[r] * 64 + lane];
#pragma unroll
        for (int r = 0; r < 8; ++r) {
            union { uint u; _Float16 h[2]; } cv;
            cv.u = (k + 1 < dg8[r]) ? tB[r] : 0u;
            acc8[r].x += (float)cv.h[0];
            acc8[r].y += (float)cv.h[1];
        }
#pragma unroll
        for (int r = 0; r < 8; ++r) sB[r] = sM[r];
    }

    __syncthreads();   // make Phase-A1 Acc writes visible before RMW
    const int j = lane * 2;
#pragma unroll
    for (int r = 0; r < 8; ++r) {
        float* a = &Acc[(wave * 8 + r) * ALD + j];
        a[0] += acc8[r].x;
        a[1] += acc8[r].y;
    }
}

// ---------------------------------------------------------------------------
// Fused GIN layer (layers 0..2 of the pipeline): C = (gather?) @ W^T + b.
// cat buffer is [GN,384] (blocks 0..2); layer 3 is fused into gin_final.
// __launch_bounds__(512,8): pin VGPR<=64 so LDS (33792B) admits 4 blocks/CU.
// ---------------------------------------------------------------------------
template<bool GATHER>
__global__ __launch_bounds__(512, 8) void gin_layer(
    const float* __restrict__ H, int ldH,      // fp32 self rows (cat block / x)
    const _Float16* __restrict__ HfIn,         // dense fp16 copy for gather
    const int* __restrict__ row_start,
    const int* __restrict__ deg,
    const int* __restrict__ csr,
    const __bf16* __restrict__ Whi,            // [128,128]
    const __bf16* __restrict__ Wlo,
    const float* __restrict__ bias,            // [128]
    float* __restrict__ C, int ldC,
    _Float16* __restrict__ HfOut)              // dense fp16 copy of C
{
    constexpr int K = 128;

    __shared__ float Acc[64 * ALD];      // 33792 B

    const int tid  = threadIdx.x;
    const int wave = tid >> 6;
    const int lane = tid & 63;
    const int row0 = blockIdx.x * 64;
    const int wm   = (wave >> 2) * 32;   // 0/32
    const int wn   = (wave & 3) * 32;    // 0/32/64/96
    const int quad = lane >> 4;
    const int l15  = lane & 15;

    // ---- Phase A1: Acc = self rows ----
#pragma unroll
    for (int p = 0; p < 4; ++p) {
        const int q  = tid + p * 512;
        const int r  = q >> 5;
        const int c4 = (q & 31) * 4;
        float4 v = make_float4(0.f, 0.f, 0.f, 0.f);
        if (row0 + r < GN) v = *(const float4*)(H + (size_t)(row0 + r) * ldH + c4);
        *(float4*)&Acc[r * ALD + c4] = v;
    }

    // ---- Phase A2 (GATHER): pipelined 8-row fp16 gather ----
    if (GATHER)
        gather8_f16((const uint*)HfIn, row_start, deg, csr, row0, wave, lane, Acc);
    __syncthreads();

    // ---- Phase B: 3-term MFMA with in-register hi/lo split of A ----
    f32x4 acc[2][2];
#pragma unroll
    for (int i = 0; i < 2; ++i)
#pragma unroll
        for (int j = 0; j < 2; ++j) acc[i][j] = (f32x4)(0.0f);

#pragma unroll
    for (int ks = 0; ks < 4; ++ks) {
        const int kt = ks * 32 + quad * 8;
        bf16x8 ahi[2], alo[2];
#pragma unroll
        for (int mt = 0; mt < 2; ++mt) {
            const float* ap = &Acc[(wm + mt * 16 + l15) * ALD + kt];
            const f32x4 p = *(const f32x4*)ap;
            const f32x4 q = *(const f32x4*)(ap + 4);
#pragma unroll
            for (int e = 0; e < 4; ++e) {
                const __bf16 hp = (__bf16)p[e];
                const __bf16 hq = (__bf16)q[e];
                ahi[mt][e]     = hp;
                ahi[mt][e + 4] = hq;
                alo[mt][e]     = (__bf16)(p[e] - (float)hp);
                alo[mt][e + 4] = (__bf16)(q[e] - (float)hq);
            }
        }
        bf16x8 whi[2], wlo[2];
#pragma unroll
        for (int nt = 0; nt < 2; ++nt) {
            const int n = wn + nt * 16 + l15;
            whi[nt] = *(const bf16x8*)(Whi + (size_t)n * K + kt);
            wlo[nt] = *(const bf16x8*)(Wlo + (size_t)n * K + kt);
        }
#pragma unroll
        for (int mt = 0; mt < 2; ++mt)
#pragma unroll
            for (int nt = 0; nt < 2; ++nt) {
                acc[mt][nt] = __builtin_amdgcn_mfma_f32_16x16x32_bf16(
                    ahi[mt], whi[nt], acc[mt][nt], 0, 0, 0);
                acc[mt][nt] = __builtin_amdgcn_mfma_f32_16x16x32_bf16(
                    ahi[mt], wlo[nt], acc[mt][nt], 0, 0, 0);
                acc[mt][nt] = __builtin_amdgcn_mfma_f32_16x16x32_bf16(
                    alo[mt], whi[nt], acc[mt][nt], 0, 0, 0);
            }
    }
    __syncthreads();

    // ---- Phase C: epilogue via Acc, coalesced fp32 + fp16 stores ----
#pragma unroll
    for (int nt = 0; nt < 2; ++nt) {
        const int col = wn + nt * 16 + l15;
        const float b = bias[col];
#pragma unroll
        for (int mt = 0; mt < 2; ++mt)
#pragma unroll
            for (int r4 = 0; r4 < 4; ++r4)
                Acc[(wm + mt * 16 + quad * 4 + r4) * ALD + col] = acc[mt][nt][r4] + b;
    }
    __syncthreads();
#pragma unroll
    for (int p = 0; p < 4; ++p) {
        const int q  = tid + p * 512;
        const int r  = q >> 5;
        const int c4 = (q & 31) * 4;
        const int gr = row0 + r;
        if (gr < GN)
            *(float4*)(C + (size_t)gr * ldC + c4) = *(const float4*)&Acc[r * ALD + c4];
    }
#pragma unroll
    for (int p = 0; p < 2; ++p) {
        const int q = tid + p * 512;
        const int r = q >> 4;
        const int g = (q & 15) * 8;
        const int gr = row0 + r;
        if (gr < GN) {
            const float4 a = *(const float4*)&Acc[r * ALD + g];
            const float4 b = *(const float4*)&Acc[r * ALD + g + 4];
            f16x8 o = {(_Float16)a.x, (_Float16)a.y, (_Float16)a.z, (_Float16)a.w,
                       (_Float16)b.x, (_Float16)b.y, (_Float16)b.z, (_Float16)b.w};
            *(f16x8*)&HfOut[(size_t)gr * 128 + g] = o;
        }
    }
}

// ---------------------------------------------------------------------------
// Fused layer 3 + output projection + softmax.
// Cst now ALIASES Acc (Cst is only live after all B2 reads of Acc complete,
// enforced by the extra __syncthreads() after the B2 MFMA loop). LDS drops
// 51200 -> 33792 B => 4 blocks/CU (was 3), with __launch_bounds__(512,8)
// pinning VGPR<=64 so the LDS limit is the binding one.
// ---------------------------------------------------------------------------
__global__ __launch_bounds__(512, 8) void gin_final(
    const float* __restrict__ cat3,            // [GN,384]
    const _Float16* __restrict__ HfIn,         // h2 fp16
    const int* __restrict__ row_start,
    const int* __restrict__ deg,
    const int* __restrict__ csr,
    const __bf16* __restrict__ Whi3,           // Wc[2] planes [128,128]
    const __bf16* __restrict__ Wlo3,
    const float* __restrict__ b3,              // [128]
    const __bf16* __restrict__ WhiO,           // W_out planes [64,512]
    const __bf16* __restrict__ WloO,
    const float* __restrict__ bO,              // [64]
    float* __restrict__ out)                   // [GN,64]
{
    constexpr int CLD = 68;

    __shared__ float Smem[64 * ALD];     // 33792 B; Acc and Cst time-share it
    float* const Acc = Smem;
    float* const Cst = Smem;             // 64*CLD*4 = 17408 B <= 33792 B

    const int tid  = threadIdx.x;
    const int wave = tid >> 6;
    const int lane = tid & 63;
    const int row0 = blockIdx.x * 64;
    const int quad = lane >> 4;
    const int l15  = lane & 15;

    // ---- Phase A1: self rows = cat3 block 2 ----
#pragma unroll
    for (int p = 0; p < 4; ++p) {
        const int q  = tid + p * 512;
        const int r  = q >> 5;
        const int c4 = (q & 31) * 4;
        float4 v = make_float4(0.f, 0.f, 0.f, 0.f);
        if (row0 + r < GN)
            v = *(const float4*)(cat3 + (size_t)(row0 + r) * 384 + 256 + c4);
        *(float4*)&Acc[r * ALD + c4] = v;
    }

    // ---- Phase A2: pipelined gather ----
    gather8_f16((const uint*)HfIn, row_start, deg, csr, row0, wave, lane, Acc);
    __syncthreads();

    // ---- Phase B1: GEMM1 (K=128) -> h3, 2m x 4n wave grid ----
    const int wm = (wave >> 2) * 32;
    const int wn = (wave & 3) * 32;
    f32x4 acc1[2][2];
#pragma unroll
    for (int i = 0; i < 2; ++i)
#pragma unroll
        for (int j = 0; j < 2; ++j) acc1[i][j] = (f32x4)(0.0f);

#pragma unroll
    for (int ks = 0; ks < 4; ++ks) {
        const int kt = ks * 32 + quad * 8;
        bf16x8 ahi[2], alo[2];
#pragma unroll
        for (int mt = 0; mt < 2; ++mt) {
            const float* ap = &Acc[(wm + mt * 16 + l15) * ALD + kt];
            const f32x4 p = *(const f32x4*)ap;
            const f32x4 q = *(const f32x4*)(ap + 4);
#pragma unroll
            for (int e = 0; e < 4; ++e) {
                const __bf16 hp = (__bf16)p[e];
                const __bf16 hq = (__bf16)q[e];
                ahi[mt][e]     = hp;
                ahi[mt][e + 4] = hq;
                alo[mt][e]     = (__bf16)(p[e] - (float)hp);
                alo[mt][e + 4] = (__bf16)(q[e] - (float)hq);
            }
        }
        bf16x8 whi[2], wlo[2];
#pragma unroll
        for (int nt = 0; nt < 2; ++nt) {
            const int n = wn + nt * 16 + l15;
            whi[nt] = *(const bf16x8*)(Whi3 + (size_t)n * 128 + kt);
            wlo[nt] = *(const bf16x8*)(Wlo3 + (size_t)n * 128 + kt);
        }
#pragma unroll
        for (int mt = 0; mt < 2; ++mt)
#pragma unroll
            for (int nt = 0; nt < 2; ++nt) {
                acc1[mt][nt] = __builtin_amdgcn_mfma_f32_16x16x32_bf16(
                    ahi[mt], whi[nt], acc1[mt][nt], 0, 0, 0);
                acc1[mt][nt] = __builtin_amdgcn_mfma_f32_16x16x32_bf16(
                    ahi[mt], wlo[nt], acc1[mt][nt], 0, 0, 0);
                acc1[mt][nt] = __builtin_amdgcn_mfma_f32_16x16x32_bf16(
                    alo[mt], whi[nt], acc1[mt][nt], 0, 0, 0);
            }
    }
    __syncthreads();

    // h3 + b3 -> Acc (overwrites gather input; all reads done)
#pragma unroll
    for (int nt = 0; nt < 2; ++nt) {
        const int col = wn + nt * 16 + l15;
        const float b = b3[col];
#pragma unroll
        for (int mt = 0; mt < 2; ++mt)
#pragma unroll
            for (int r4 = 0; r4 < 4; ++r4)
                Acc[(wm + mt * 16 + quad * 4 + r4) * ALD + col] = acc1[mt][nt][r4] + b;
    }
    __syncthreads();

    // ---- Phase B2: GEMM2 (K=512), 2m x 2n x 2k wave grid ----
    const int wk  = wave & 1;
    const int wn2 = ((wave >> 1) & 1) * 32;
    const int wm2 = ((wave >> 2) & 1) * 32;
    f32x4 acc2[2][2];
#pragma unroll
    for (int i = 0; i < 2; ++i)
#pragma unroll
        for (int j = 0; j < 2; ++j) acc2[i][j] = (f32x4)(0.0f);

#pragma unroll
    for (int ks = 0; ks < 8; ++ks) {
        const int kg = wk * 256 + ks * 32 + quad * 8;
        bf16x8 ahi[2], alo[2];
#pragma unroll
        for (int mt = 0; mt < 2; ++mt) {
            const int row = wm2 + mt * 16 + l15;
            f32x4 p, q;
            if (kg < 384) {
                // direct global fragment (rows past GN read safe in-ws bytes;
                // their outputs are never stored)
                const float* ap = cat3 + (size_t)(row0 + row) * 384 + kg;
                p = *(const f32x4*)ap;
                q = *(const f32x4*)(ap + 4);
            } else {
                const float* ap = &Acc[row * ALD + (kg - 384)];
                p = *(const f32x4*)ap;
                q = *(const f32x4*)(ap + 4);
            }
#pragma unroll
            for (int e = 0; e < 4; ++e) {
                const __bf16 hp = (__bf16)p[e];
                const __bf16 hq = (__bf16)q[e];
                ahi[mt][e]     = hp;
                ahi[mt][e + 4] = hq;
                alo[mt][e]     = (__bf16)(p[e] - (float)hp);
                alo[mt][e + 4] = (__bf16)(q[e] - (float)hq);
            }
        }
        bf16x8 whi[2], wlo[2];
#pragma unroll
        for (int nt = 0; nt < 2; ++nt) {
            const int n = wn2 + nt * 16 + l15;
            whi[nt] = *(const bf16x8*)(WhiO + (size_t)n * 512 + kg);
            wlo[nt] = *(const bf16x8*)(WloO + (size_t)n * 512 + kg);
        }
#pragma unroll
        for (int mt = 0; mt < 2; ++mt)
#pragma unroll
            for (int nt = 0; nt < 2; ++nt) {
                acc2[mt][nt] = __builtin_amdgcn_mfma_f32_16x16x32_bf16(
                    ahi[mt], whi[nt], acc2[mt][nt], 0, 0, 0);
                acc2[mt][nt] = __builtin_amdgcn_mfma_f32_16x16x32_bf16(
                    ahi[mt], wlo[nt], acc2[mt][nt], 0, 0, 0);
                acc2[mt][nt] = __builtin_amdgcn_mfma_f32_16x16x32_bf16(
                    alo[mt], whi[nt], acc2[mt][nt], 0, 0, 0);
            }
    }

    // All B2 reads of Acc are done before Cst (alias of Acc) is written.
    __syncthreads();

    // ---- k-half reduction in Cst ----
    if (wk == 1) {
#pragma unroll
        for (int nt = 0; nt < 2; ++nt)
#pragma unroll
            for (int mt = 0; mt < 2; ++mt)
#pragma unroll
                for (int r4 = 0; r4 < 4; ++r4)
                    Cst[(wm2 + mt * 16 + quad * 4 + r4) * CLD + wn2 + nt * 16 + l15]
                        = acc2[mt][nt][r4];
    }
    __syncthreads();
    if (wk == 0) {
#pragma unroll
        for (int nt = 0; nt < 2; ++nt) {
            const int col = wn2 + nt * 16 + l15;
            const float b = bO[col];
#pragma unroll
            for (int mt = 0; mt < 2; ++mt)
#pragma unroll
                for (int r4 = 0; r4 < 4; ++r4) {
                    const int idx = (wm2 + mt * 16 + quad * 4 + r4) * CLD + col;
                    Cst[idx] = Cst[idx] + acc2[mt][nt][r4] + b;
                }
        }
    }
    __syncthreads();

    // ---- Phase C: softmax, one wave per row (8 rows/wave) ----
    for (int i = 0; i < 8; ++i) {
        const int r = wave * 8 + i;
        const float v = Cst[r * CLD + lane];
        float m = v;
#pragma unroll
        for (int off = 32; off > 0; off >>= 1) m = fmaxf(m, __shfl_xor(m, off));
        const float e = __expf(v - m);
        float s = e;
#pragma unroll
        for (int off = 32; off > 0; off >>= 1) s += __shfl_xor(s, off);
        const int gr = row0 + r;
        if (gr < GN) out[(size_t)gr * 64 + lane] = e / s;
    }
}

// ---------------------------------------------------------------------------
// CSR construction (graph static; built once per launch)
// ---------------------------------------------------------------------------
__global__ __launch_bounds__(256) void count_deg(const int* __restrict__ dst,
                                                 int* __restrict__ deg)
{
    const int e = blockIdx.x * 256 + threadIdx.x;
    if (e < GE) atomicAdd(&deg[dst[e]], 1);
}

__global__ __launch_bounds__(256) void scan_pass1(const int* __restrict__ deg,
                                                  int* __restrict__ excl,
                                                  int* __restrict__ blockSums)
{
    __shared__ int s[256];
    const int t = threadIdx.x;
    const int base = blockIdx.x * 1024 + t * 4;

    int4 v = make_int4(0, 0, 0, 0);
    if (base + 3 < GN) {
        v = *(const int4*)(deg + base);
    } else {
        if (base + 0 < GN) v.x = deg[base + 0];
        if (base + 1 < GN) v.y = deg[base + 1];
        if (base + 2 < GN) v.z = deg[base + 2];
        if (base + 3 < GN) v.w = deg[base + 3];
    }
    const int mysum = v.x + v.y + v.z + v.w;
    s[t] = mysum;
    __syncthreads();
    for (int off = 1; off < 256; off <<= 1) {
        const int val = (t >= off) ? s[t - off] : 0;
        __syncthreads();
        s[t] += val;
        __syncthreads();
    }
    int4 o;
    o.x = s[t] - mysum;
    o.y = o.x + v.x;
    o.z = o.y + v.y;
    o.w = o.z + v.z;
    if (base + 3 < GN) {
        *(int4*)(excl + base) = o;
    } else {
        if (base + 0 < GN) excl[base + 0] = o.x;
        if (base + 1 < GN) excl[base + 1] = o.y;
        if (base + 2 < GN) excl[base + 2] = o.z;
        if (base + 3 < GN) excl[base + 3] = o.w;
    }
    if (t == 255) blockSums[blockIdx.x] = s[255];
}

__global__ __launch_bounds__(128) void scan_pass2(const int* __restrict__ blockSums,
                                                  int* __restrict__ blockOffs, int n)
{
    __shared__ int s[128];
    const int t = threadIdx.x;
    const int v = (t < n) ? blockSums[t] : 0;
    s[t] = v;
    __syncthreads();
    for (int off = 1; off < 128; off <<= 1) {
        const int val = (t >= off) ? s[t - off] : 0;
        __syncthreads();
        s[t] += val;
        __syncthreads();
    }
    if (t < n) blockOffs[t] = s[t] - v;
}

__global__ __launch_bounds__(256) void scan_pass3(int* __restrict__ excl,
                                                  const int* __restrict__ blockOffs,
                                                  int* __restrict__ cursor)
{
    const int i = blockIdx.x * 256 + threadIdx.x;
    if (i >= GN) return;
    const int v = excl[i] + blockOffs[i >> 10];
    excl[i]   = v;
    cursor[i] = v;
}

__global__ __launch_bounds__(256) void fill_csr(const int* __restrict__ src,
                                                const int* __restrict__ dst,
                                                int* __restrict__ cursor,
                                                int* __restrict__ csr)
{
    const int e = blockIdx.x * 256 + threadIdx.x;
    if (e >= GE) return;
    const int pos = atomicAdd(&cursor[dst[e]], 1);
    csr[pos] = src[e];
}

extern "C" void kernel_launch(void* const* d_in, const int* in_sizes, int n_in,
                              void* d_out, int out_size, void* d_ws, size_t ws_size,
                              hipStream_t stream)
{
    const float* x       = (const float*)d_in[0];
    const int*   src     = (const int*)d_in[1];            // edge_index[0]
    const int*   dst     = ((const int*)d_in[1]) + GE;     // edge_index[1]
    const float* W_in    = (const float*)d_in[2];
    const float* b_in    = (const float*)d_in[3];
    const float* W_convs = (const float*)d_in[4];          // [3,128,128]
    const float* b_convs = (const float*)d_in[5];          // [3,128]
    const float* W_out   = (const float*)d_in[6];          // [64,512]
    const float* b_out   = (const float*)d_in[7];
    float*       out     = (float*)d_out;                  // [GN,64]

    // d_ws layout (~209 MB of the >=256 MB workspace):
    //   cat3 [GN,384] fp32 | Hf0 | Hf1 (fp16 [GN,128] each) | CSR scratch
    //   (csr has CSR_PAD zeroed tail ints for the pipelined gather) |
    //   hi/lo weight planes (98304 bf16 each).  d_out holds ONLY the output.
    float*    cat3 = (float*)d_ws;
    _Float16* Hf0  = (_Float16*)(cat3 + (size_t)GN * 384);
    _Float16* Hf1  = Hf0 + (size_t)GN * 128;
    int*      deg       = (int*)(Hf1 + (size_t)GN * 128);
    int*      row_start = deg + GN;
    int*      cursor    = row_start + GN;
    int*      blockSums = cursor + GN;
    int*      blockOffs = blockSums + 128;
    int*      csr       = blockOffs + 128;
    __bf16*   Whi       = (__bf16*)(csr + GE + CSR_PAD);   // 98304 bf16
    __bf16*   Wlo       = Whi + 98304;

    const dim3 blk(256);
    const dim3 gblk(512);
    const int edge_blocks  = (GE + 255) / 256;
    const int node_blocks  = (GN + 255) / 256;
    const int layer_blocks = (GN + 63) / 64;     // 1563

    // --- CSR build (pad tail zeroed so pipelined gather over-reads node 0) ---
    hipMemsetAsync(deg, 0, GN * sizeof(int), stream);
    hipMemsetAsync(csr + GE, 0, CSR_PAD * sizeof(int), stream);
    count_deg<<<edge_blocks, blk, 0, stream>>>(dst, deg);
    scan_pass1<<<SCAN_NBLK, blk, 0, stream>>>(deg, row_start, blockSums);
    scan_pass2<<<1, 128, 0, stream>>>(blockSums, blockOffs, SCAN_NBLK);
    scan_pass3<<<node_blocks, blk, 0, stream>>>(row_start, blockOffs, cursor);
    fill_csr<<<edge_blocks, blk, 0, stream>>>(src, dst, cursor, csr);

    // --- weight pre-conversion (all hi/lo planes incl. W_out) ---
    convert_w<<<(98304 + 255) / 256, blk, 0, stream>>>(W_in, W_convs, W_out, Whi, Wlo);

    // --- input projection -> cat3 block 0 + Hf0 ---
    gin_layer<false><<<layer_blocks, gblk, 0, stream>>>(
        x, 128, nullptr, nullptr, nullptr, nullptr,
        Whi, Wlo, b_in, cat3, 384, Hf0);

    // --- layers 1..2: fp16 gather (ping-pong Hf) + linear ---
    gin_layer<true><<<layer_blocks, gblk, 0, stream>>>(
        cat3, 384, Hf0, row_start, deg, csr,
        Whi + 16384, Wlo + 16384, b_convs, cat3 + 128, 384, Hf1);
    gin_layer<true><<<layer_blocks, gblk, 0, stream>>>(
        cat3 + 128, 384, Hf1, row_start, deg, csr,
        Whi + 32768, Wlo + 32768, b_convs + 128, cat3 + 256, 384, Hf0);

    // --- fused layer 3 + output projection + softmax -> d_out ---
    gin_final<<<layer_blocks, gblk, 0, stream>>>(
        cat3, Hf0, row_start, deg, csr,
        Whi + 49152, Wlo + 49152, b_convs + 256,
        Whi + 65536, Wlo + 65536, b_out, out);
}

// Round 2
// 524.578 us; speedup vs baseline: 1.8388x; 1.8388x over previous
//
#include <hip/hip_runtime.h>
#include <hip/hip_bf16.h>
#include <hip/hip_fp16.h>

#define GN 100000
#define GE 600000
#define SCAN_NBLK 98   // ceil(GN / 1024)
#define ALD 132        // fp32 LDS leading dim: 128 + 4

typedef __bf16    bf16x8 __attribute__((ext_vector_type(8)));
typedef __bf16    bf16x4 __attribute__((ext_vector_type(4)));
typedef _Float16  f16x8  __attribute__((ext_vector_type(8)));
typedef float     f32x4  __attribute__((ext_vector_type(4)));

// ---------------------------------------------------------------------------
// Weight pre-conversion: fp32 -> (hi, lo) bf16 planes, ONCE per launch.
// [0,16384) W_in[128,128]; [16384,65536) W_convs[3][128][128];
// [65536,98304) W_out[64,512]. All row-major [OC, K].
// ---------------------------------------------------------------------------
__global__ __launch_bounds__(256) void convert_w(
    const float* __restrict__ Win, const float* __restrict__ Wc,
    const float* __restrict__ Wout,
    __bf16* __restrict__ hi, __bf16* __restrict__ lo)
{
    const int i = blockIdx.x * 256 + threadIdx.x;
    if (i >= 98304) return;
    float v;
    if (i < 16384)      v = Win[i];
    else if (i < 65536) v = Wc[i - 16384];
    else                v = Wout[i - 65536];
    const __bf16 h = (__bf16)v;
    hi[i] = h;
    lo[i] = (__bf16)(v - (float)h);
}

// ---------------------------------------------------------------------------
// Branchless pipelined 8-row fp16 gather (round-0 structure: 8 outstanding
// row loads + next-index prefetch; fits in ~52 VGPR under (512,4)).
// Ends with __syncthreads() + accumulate into Acc rows [wave*8, wave*8+8).
// ---------------------------------------------------------------------------
__device__ __forceinline__ void gather8_f16(
    const uint* __restrict__ Hw,
    const int* __restrict__ row_start,
    const int* __restrict__ deg,
    const int* __restrict__ csr,
    const int row0, const int wave, const int lane,
    float* __restrict__ Acc)
{
    float2 acc8[8];
    int start8[8], deg8[8];
    int maxd = 0;
#pragma unroll
    for (int r = 0; r < 8; ++r) {
        acc8[r] = make_float2(0.f, 0.f);
        const int v = row0 + wave * 8 + r;
        start8[r] = (v < GN) ? row_start[v] : 0;
        deg8[r]   = (v < GN) ? deg[v] : 0;
        maxd = max(maxd, deg8[r]);
    }
    int scur[8];
#pragma unroll
    for (int r = 0; r < 8; ++r) {
        const int s = csr[start8[r]];
        scur[r] = min(max(s, 0), GN - 1);
    }
    for (int k = 0; k < maxd; ++k) {
        int snext[8];
#pragma unroll
        for (int r = 0; r < 8; ++r) {
            const int kk = max(min(k + 1, deg8[r] - 1), 0);
            snext[r] = csr[start8[r] + kk];
        }
        uint t[8];
#pragma unroll
        for (int r = 0; r < 8; ++r)
            t[r] = Hw[(size_t)scur[r] * 64 + lane];
#pragma unroll
        for (int r = 0; r < 8; ++r) {
            const float m = (k < deg8[r]) ? 1.f : 0.f;
            union { uint u; _Float16 h[2]; } cv;
            cv.u = t[r];
            acc8[r].x = fmaf(m, (float)cv.h[0], acc8[r].x);
            acc8[r].y = fmaf(m, (float)cv.h[1], acc8[r].y);
            scur[r] = min(max(snext[r], 0), GN - 1);
        }
    }
    __syncthreads();   // make Phase-A1 Acc writes visible before RMW
    const int j = lane * 2;
#pragma unroll
    for (int r = 0; r < 8; ++r) {
        float* a = &Acc[(wave * 8 + r) * ALD + j];
        a[0] += acc8[r].x;
        a[1] += acc8[r].y;
    }
}

// ---------------------------------------------------------------------------
// Fused GIN layer (layers 0..2 of the pipeline): C = (gather?) @ W^T + b.
// cat buffer is [GN,384] (blocks 0..2); layer 3 is fused into gin_final.
// ---------------------------------------------------------------------------
template<bool GATHER>
__global__ __launch_bounds__(512, 4) void gin_layer(
    const float* __restrict__ H, int ldH,      // fp32 self rows (cat block / x)
    const _Float16* __restrict__ HfIn,         // dense fp16 copy for gather
    const int* __restrict__ row_start,
    const int* __restrict__ deg,
    const int* __restrict__ csr,
    const __bf16* __restrict__ Whi,            // [128,128]
    const __bf16* __restrict__ Wlo,
    const float* __restrict__ bias,            // [128]
    float* __restrict__ C, int ldC,
    _Float16* __restrict__ HfOut)              // dense fp16 copy of C
{
    constexpr int K = 128;

    __shared__ float Acc[64 * ALD];      // 33792 B

    const int tid  = threadIdx.x;
    const int wave = tid >> 6;
    const int lane = tid & 63;
    const int row0 = blockIdx.x * 64;
    const int wm   = (wave >> 2) * 32;   // 0/32
    const int wn   = (wave & 3) * 32;    // 0/32/64/96
    const int quad = lane >> 4;
    const int l15  = lane & 15;

    // ---- Phase A1: Acc = self rows ----
#pragma unroll
    for (int p = 0; p < 4; ++p) {
        const int q  = tid + p * 512;
        const int r  = q >> 5;
        const int c4 = (q & 31) * 4;
        float4 v = make_float4(0.f, 0.f, 0.f, 0.f);
        if (row0 + r < GN) v = *(const float4*)(H + (size_t)(row0 + r) * ldH + c4);
        *(float4*)&Acc[r * ALD + c4] = v;
    }

    // ---- Phase A2 (GATHER): 8-row fp16 gather ----
    if (GATHER)
        gather8_f16((const uint*)HfIn, row_start, deg, csr, row0, wave, lane, Acc);
    __syncthreads();

    // ---- Phase B: 3-term MFMA with in-register hi/lo split of A ----
    f32x4 acc[2][2];
#pragma unroll
    for (int i = 0; i < 2; ++i)
#pragma unroll
        for (int j = 0; j < 2; ++j) acc[i][j] = (f32x4)(0.0f);

#pragma unroll
    for (int ks = 0; ks < 4; ++ks) {
        const int kt = ks * 32 + quad * 8;
        bf16x8 ahi[2], alo[2];
#pragma unroll
        for (int mt = 0; mt < 2; ++mt) {
            const float* ap = &Acc[(wm + mt * 16 + l15) * ALD + kt];
            const f32x4 p = *(const f32x4*)ap;
            const f32x4 q = *(const f32x4*)(ap + 4);
#pragma unroll
            for (int e = 0; e < 4; ++e) {
                const __bf16 hp = (__bf16)p[e];
                const __bf16 hq = (__bf16)q[e];
                ahi[mt][e]     = hp;
                ahi[mt][e + 4] = hq;
                alo[mt][e]     = (__bf16)(p[e] - (float)hp);
                alo[mt][e + 4] = (__bf16)(q[e] - (float)hq);
            }
        }
        bf16x8 whi[2], wlo[2];
#pragma unroll
        for (int nt = 0; nt < 2; ++nt) {
            const int n = wn + nt * 16 + l15;
            whi[nt] = *(const bf16x8*)(Whi + (size_t)n * K + kt);
            wlo[nt] = *(const bf16x8*)(Wlo + (size_t)n * K + kt);
        }
#pragma unroll
        for (int mt = 0; mt < 2; ++mt)
#pragma unroll
            for (int nt = 0; nt < 2; ++nt) {
                acc[mt][nt] = __builtin_amdgcn_mfma_f32_16x16x32_bf16(
                    ahi[mt], whi[nt], acc[mt][nt], 0, 0, 0);
                acc[mt][nt] = __builtin_amdgcn_mfma_f32_16x16x32_bf16(
                    ahi[mt], wlo[nt], acc[mt][nt], 0, 0, 0);
                acc[mt][nt] = __builtin_amdgcn_mfma_f32_16x16x32_bf16(
                    alo[mt], whi[nt], acc[mt][nt], 0, 0, 0);
            }
    }
    __syncthreads();

    // ---- Phase C: epilogue via Acc, coalesced fp32 + fp16 stores ----
#pragma unroll
    for (int nt = 0; nt < 2; ++nt) {
        const int col = wn + nt * 16 + l15;
        const float b = bias[col];
#pragma unroll
        for (int mt = 0; mt < 2; ++mt)
#pragma unroll
            for (int r4 = 0; r4 < 4; ++r4)
                Acc[(wm + mt * 16 + quad * 4 + r4) * ALD + col] = acc[mt][nt][r4] + b;
    }
    __syncthreads();
#pragma unroll
    for (int p = 0; p < 4; ++p) {
        const int q  = tid + p * 512;
        const int r  = q >> 5;
        const int c4 = (q & 31) * 4;
        const int gr = row0 + r;
        if (gr < GN)
            *(float4*)(C + (size_t)gr * ldC + c4) = *(const float4*)&Acc[r * ALD + c4];
    }
#pragma unroll
    for (int p = 0; p < 2; ++p) {
        const int q = tid + p * 512;
        const int r = q >> 4;
        const int g = (q & 15) * 8;
        const int gr = row0 + r;
        if (gr < GN) {
            const float4 a = *(const float4*)&Acc[r * ALD + g];
            const float4 b = *(const float4*)&Acc[r * ALD + g + 4];
            f16x8 o = {(_Float16)a.x, (_Float16)a.y, (_Float16)a.z, (_Float16)a.w,
                       (_Float16)b.x, (_Float16)b.y, (_Float16)b.z, (_Float16)b.w};
            *(f16x8*)&HfOut[(size_t)gr * 128 + g] = o;
        }
    }
}

// ---------------------------------------------------------------------------
// Fused layer 3 + output projection + softmax.
// Cst ALIASES Acc (Cst is only live after all B2 reads of Acc complete,
// enforced by the extra __syncthreads() after the B2 MFMA loop). LDS drops
// 51200 -> 33792 B => 4 blocks/CU (was 3) at VGPR<=64 (round-0 build: 52).
// ---------------------------------------------------------------------------
__global__ __launch_bounds__(512, 4) void gin_final(
    const float* __restrict__ cat3,            // [GN,384]
    const _Float16* __restrict__ HfIn,         // h2 fp16
    const int* __restrict__ row_start,
    const int* __restrict__ deg,
    const int* __restrict__ csr,
    const __bf16* __restrict__ Whi3,           // Wc[2] planes [128,128]
    const __bf16* __restrict__ Wlo3,
    const float* __restrict__ b3,              // [128]
    const __bf16* __restrict__ WhiO,           // W_out planes [64,512]
    const __bf16* __restrict__ WloO,
    const float* __restrict__ bO,              // [64]
    float* __restrict__ out)                   // [GN,64]
{
    constexpr int CLD = 68;

    __shared__ float Smem[64 * ALD];     // 33792 B; Acc and Cst time-share it
    float* const Acc = Smem;
    float* const Cst = Smem;             // 64*CLD*4 = 17408 B <= 33792 B

    const int tid  = threadIdx.x;
    const int wave = tid >> 6;
    const int lane = tid & 63;
    const int row0 = blockIdx.x * 64;
    const int quad = lane >> 4;
    const int l15  = lane & 15;

    // ---- Phase A1: self rows = cat3 block 2 ----
#pragma unroll
    for (int p = 0; p < 4; ++p) {
        const int q  = tid + p * 512;
        const int r  = q >> 5;
        const int c4 = (q & 31) * 4;
        float4 v = make_float4(0.f, 0.f, 0.f, 0.f);
        if (row0 + r < GN)
            v = *(const float4*)(cat3 + (size_t)(row0 + r) * 384 + 256 + c4);
        *(float4*)&Acc[r * ALD + c4] = v;
    }

    // ---- Phase A2: gather ----
    gather8_f16((const uint*)HfIn, row_start, deg, csr, row0, wave, lane, Acc);
    __syncthreads();

    // ---- Phase B1: GEMM1 (K=128) -> h3, 2m x 4n wave grid ----
    const int wm = (wave >> 2) * 32;
    const int wn = (wave & 3) * 32;
    f32x4 acc1[2][2];
#pragma unroll
    for (int i = 0; i < 2; ++i)
#pragma unroll
        for (int j = 0; j < 2; ++j) acc1[i][j] = (f32x4)(0.0f);

#pragma unroll
    for (int ks = 0; ks < 4; ++ks) {
        const int kt = ks * 32 + quad * 8;
        bf16x8 ahi[2], alo[2];
#pragma unroll
        for (int mt = 0; mt < 2; ++mt) {
            const float* ap = &Acc[(wm + mt * 16 + l15) * ALD + kt];
            const f32x4 p = *(const f32x4*)ap;
            const f32x4 q = *(const f32x4*)(ap + 4);
#pragma unroll
            for (int e = 0; e < 4; ++e) {
                const __bf16 hp = (__bf16)p[e];
                const __bf16 hq = (__bf16)q[e];
                ahi[mt][e]     = hp;
                ahi[mt][e + 4] = hq;
                alo[mt][e]     = (__bf16)(p[e] - (float)hp);
                alo[mt][e + 4] = (__bf16)(q[e] - (float)hq);
            }
        }
        bf16x8 whi[2], wlo[2];
#pragma unroll
        for (int nt = 0; nt < 2; ++nt) {
            const int n = wn + nt * 16 + l15;
            whi[nt] = *(const bf16x8*)(Whi3 + (size_t)n * 128 + kt);
            wlo[nt] = *(const bf16x8*)(Wlo3 + (size_t)n * 128 + kt);
        }
#pragma unroll
        for (int mt = 0; mt < 2; ++mt)
#pragma unroll
            for (int nt = 0; nt < 2; ++nt) {
                acc1[mt][nt] = __builtin_amdgcn_mfma_f32_16x16x32_bf16(
                    ahi[mt], whi[nt], acc1[mt][nt], 0, 0, 0);
                acc1[mt][nt] = __builtin_amdgcn_mfma_f32_16x16x32_bf16(
                    ahi[mt], wlo[nt], acc1[mt][nt], 0, 0, 0);
                acc1[mt][nt] = __builtin_amdgcn_mfma_f32_16x16x32_bf16(
                    alo[mt], whi[nt], acc1[mt][nt], 0, 0, 0);
            }
    }
    __syncthreads();

    // h3 + b3 -> Acc (overwrites gather input; all reads done)
#pragma unroll
    for (int nt = 0; nt < 2; ++nt) {
        const int col = wn + nt * 16 + l15;
        const float b = b3[col];
#pragma unroll
        for (int mt = 0; mt < 2; ++mt)
#pragma unroll
            for (int r4 = 0; r4 < 4; ++r4)
                Acc[(wm + mt * 16 + quad * 4 + r4) * ALD + col] = acc1[mt][nt][r4] + b;
    }
    __syncthreads();

    // ---- Phase B2: GEMM2 (K=512), 2m x 2n x 2k wave grid ----
    const int wk  = wave & 1;
    const int wn2 = ((wave >> 1) & 1) * 32;
    const int wm2 = ((wave >> 2) & 1) * 32;
    f32x4 acc2[2][2];
#pragma unroll
    for (int i = 0; i < 2; ++i)
#pragma unroll
        for (int j = 0; j < 2; ++j) acc2[i][j] = (f32x4)(0.0f);

#pragma unroll
    for (int ks = 0; ks < 8; ++ks) {
        const int kg = wk * 256 + ks * 32 + quad * 8;
        bf16x8 ahi[2], alo[2];
#pragma unroll
        for (int mt = 0; mt < 2; ++mt) {
            const int row = wm2 + mt * 16 + l15;
            f32x4 p, q;
            if (kg < 384) {
                // direct global fragment (rows past GN read safe in-ws bytes;
                // their outputs are never stored)
                const float* ap = cat3 + (size_t)(row0 + row) * 384 + kg;
                p = *(const f32x4*)ap;
                q = *(const f32x4*)(ap + 4);
            } else {
                const float* ap = &Acc[row * ALD + (kg - 384)];
                p = *(const f32x4*)ap;
                q = *(const f32x4*)(ap + 4);
            }
#pragma unroll
            for (int e = 0; e < 4; ++e) {
                const __bf16 hp = (__bf16)p[e];
                const __bf16 hq = (__bf16)q[e];
                ahi[mt][e]     = hp;
                ahi[mt][e + 4] = hq;
                alo[mt][e]     = (__bf16)(p[e] - (float)hp);
                alo[mt][e + 4] = (__bf16)(q[e] - (float)hq);
            }
        }
        bf16x8 whi[2], wlo[2];
#pragma unroll
        for (int nt = 0; nt < 2; ++nt) {
            const int n = wn2 + nt * 16 + l15;
            whi[nt] = *(const bf16x8*)(WhiO + (size_t)n * 512 + kg);
            wlo[nt] = *(const bf16x8*)(WloO + (size_t)n * 512 + kg);
        }
#pragma unroll
        for (int mt = 0; mt < 2; ++mt)
#pragma unroll
            for (int nt = 0; nt < 2; ++nt) {
                acc2[mt][nt] = __builtin_amdgcn_mfma_f32_16x16x32_bf16(
                    ahi[mt], whi[nt], acc2[mt][nt], 0, 0, 0);
                acc2[mt][nt] = __builtin_amdgcn_mfma_f32_16x16x32_bf16(
                    ahi[mt], wlo[nt], acc2[mt][nt], 0, 0, 0);
                acc2[mt][nt] = __builtin_amdgcn_mfma_f32_16x16x32_bf16(
                    alo[mt], whi[nt], acc2[mt][nt], 0, 0, 0);
            }
    }

    // All B2 reads of Acc must complete before Cst (alias of Acc) is written.
    __syncthreads();

    // ---- k-half reduction in Cst ----
    if (wk == 1) {
#pragma unroll
        for (int nt = 0; nt < 2; ++nt)
#pragma unroll
            for (int mt = 0; mt < 2; ++mt)
#pragma unroll
                for (int r4 = 0; r4 < 4; ++r4)
                    Cst[(wm2 + mt * 16 + quad * 4 + r4) * CLD + wn2 + nt * 16 + l15]
                        = acc2[mt][nt][r4];
    }
    __syncthreads();
    if (wk == 0) {
#pragma unroll
        for (int nt = 0; nt < 2; ++nt) {
            const int col = wn2 + nt * 16 + l15;
            const float b = bO[col];
#pragma unroll
            for (int mt = 0; mt < 2; ++mt)
#pragma unroll
                for (int r4 = 0; r4 < 4; ++r4) {
                    const int idx = (wm2 + mt * 16 + quad * 4 + r4) * CLD + col;
                    Cst[idx] = Cst[idx] + acc2[mt][nt][r4] + b;
                }
        }
    }
    __syncthreads();

    // ---- Phase C: softmax, one wave per row (8 rows/wave) ----
    for (int i = 0; i < 8; ++i) {
        const int r = wave * 8 + i;
        const float v = Cst[r * CLD + lane];
        float m = v;
#pragma unroll
        for (int off = 32; off > 0; off >>= 1) m = fmaxf(m, __shfl_xor(m, off));
        const float e = __expf(v - m);
        float s = e;
#pragma unroll
        for (int off = 32; off > 0; off >>= 1) s += __shfl_xor(s, off);
        const int gr = row0 + r;
        if (gr < GN) out[(size_t)gr * 64 + lane] = e / s;
    }
}

// ---------------------------------------------------------------------------
// CSR construction (graph static; built once per launch)
// ---------------------------------------------------------------------------
__global__ __launch_bounds__(256) void count_deg(const int* __restrict__ dst,
                                                 int* __restrict__ deg)
{
    const int e = blockIdx.x * 256 + threadIdx.x;
    if (e < GE) atomicAdd(&deg[dst[e]], 1);
}

__global__ __launch_bounds__(256) void scan_pass1(const int* __restrict__ deg,
                                                  int* __restrict__ excl,
                                                  int* __restrict__ blockSums)
{
    __shared__ int s[256];
    const int t = threadIdx.x;
    const int base = blockIdx.x * 1024 + t * 4;

    int4 v = make_int4(0, 0, 0, 0);
    if (base + 3 < GN) {
        v = *(const int4*)(deg + base);
    } else {
        if (base + 0 < GN) v.x = deg[base + 0];
        if (base + 1 < GN) v.y = deg[base + 1];
        if (base + 2 < GN) v.z = deg[base + 2];
        if (base + 3 < GN) v.w = deg[base + 3];
    }
    const int mysum = v.x + v.y + v.z + v.w;
    s[t] = mysum;
    __syncthreads();
    for (int off = 1; off < 256; off <<= 1) {
        const int val = (t >= off) ? s[t - off] : 0;
        __syncthreads();
        s[t] += val;
        __syncthreads();
    }
    int4 o;
    o.x = s[t] - mysum;
    o.y = o.x + v.x;
    o.z = o.y + v.y;
    o.w = o.z + v.z;
    if (base + 3 < GN) {
        *(int4*)(excl + base) = o;
    } else {
        if (base + 0 < GN) excl[base + 0] = o.x;
        if (base + 1 < GN) excl[base + 1] = o.y;
        if (base + 2 < GN) excl[base + 2] = o.z;
        if (base + 3 < GN) excl[base + 3] = o.w;
    }
    if (t == 255) blockSums[blockIdx.x] = s[255];
}

__global__ __launch_bounds__(128) void scan_pass2(const int* __restrict__ blockSums,
                                                  int* __restrict__ blockOffs, int n)
{
    __shared__ int s[128];
    const int t = threadIdx.x;
    const int v = (t < n) ? blockSums[t] : 0;
    s[t] = v;
    __syncthreads();
    for (int off = 1; off < 128; off <<= 1) {
        const int val = (t >= off) ? s[t - off] : 0;
        __syncthreads();
        s[t] += val;
        __syncthreads();
    }
    if (t < n) blockOffs[t] = s[t] - v;
}

__global__ __launch_bounds__(256) void scan_pass3(int* __restrict__ excl,
                                                  const int* __restrict__ blockOffs,
                                                  int* __restrict__ cursor)
{
    const int i = blockIdx.x * 256 + threadIdx.x;
    if (i >= GN) return;
    const int v = excl[i] + blockOffs[i >> 10];
    excl[i]   = v;
    cursor[i] = v;
}

__global__ __launch_bounds__(256) void fill_csr(const int* __restrict__ src,
                                                const int* __restrict__ dst,
                                                int* __restrict__ cursor,
                                                int* __restrict__ csr)
{
    const int e = blockIdx.x * 256 + threadIdx.x;
    if (e >= GE) return;
    const int pos = atomicAdd(&cursor[dst[e]], 1);
    csr[pos] = src[e];
}

extern "C" void kernel_launch(void* const* d_in, const int* in_sizes, int n_in,
                              void* d_out, int out_size, void* d_ws, size_t ws_size,
                              hipStream_t stream)
{
    const float* x       = (const float*)d_in[0];
    const int*   src     = (const int*)d_in[1];            // edge_index[0]
    const int*   dst     = ((const int*)d_in[1]) + GE;     // edge_index[1]
    const float* W_in    = (const float*)d_in[2];
    const float* b_in    = (const float*)d_in[3];
    const float* W_convs = (const float*)d_in[4];          // [3,128,128]
    const float* b_convs = (const float*)d_in[5];          // [3,128]
    const float* W_out   = (const float*)d_in[6];          // [64,512]
    const float* b_out   = (const float*)d_in[7];
    float*       out     = (float*)d_out;                  // [GN,64]

    // d_ws layout (~209 MB of the >=256 MB workspace):
    //   cat3 [GN,384] fp32 | Hf0 | Hf1 (fp16 [GN,128] each) | CSR scratch |
    //   hi/lo weight planes (98304 bf16 each).  d_out holds ONLY the output.
    float*    cat3 = (float*)d_ws;
    _Float16* Hf0  = (_Float16*)(cat3 + (size_t)GN * 384);
    _Float16* Hf1  = Hf0 + (size_t)GN * 128;
    int*      deg       = (int*)(Hf1 + (size_t)GN * 128);
    int*      row_start = deg + GN;
    int*      cursor    = row_start + GN;
    int*      blockSums = cursor + GN;
    int*      blockOffs = blockSums + 128;
    int*      csr       = blockOffs + 128;
    __bf16*   Whi       = (__bf16*)(csr + GE);   // 98304 bf16
    __bf16*   Wlo       = Whi + 98304;

    const dim3 blk(256);
    const dim3 gblk(512);
    const int edge_blocks  = (GE + 255) / 256;
    const int node_blocks  = (GN + 255) / 256;
    const int layer_blocks = (GN + 63) / 64;     // 1563

    // --- CSR build ---
    hipMemsetAsync(deg, 0, GN * sizeof(int), stream);
    count_deg<<<edge_blocks, blk, 0, stream>>>(dst, deg);
    scan_pass1<<<SCAN_NBLK, blk, 0, stream>>>(deg, row_start, blockSums);
    scan_pass2<<<1, 128, 0, stream>>>(blockSums, blockOffs, SCAN_NBLK);
    scan_pass3<<<node_blocks, blk, 0, stream>>>(row_start, blockOffs, cursor);
    fill_csr<<<edge_blocks, blk, 0, stream>>>(src, dst, cursor, csr);

    // --- weight pre-conversion (all hi/lo planes incl. W_out) ---
    convert_w<<<(98304 + 255) / 256, blk, 0, stream>>>(W_in, W_convs, W_out, Whi, Wlo);

    // --- input projection -> cat3 block 0 + Hf0 ---
    gin_layer<false><<<layer_blocks, gblk, 0, stream>>>(
        x, 128, nullptr, nullptr, nullptr, nullptr,
        Whi, Wlo, b_in, cat3, 384, Hf0);

    // --- layers 1..2: fp16 gather (ping-pong Hf) + linear ---
    gin_layer<true><<<layer_blocks, gblk, 0, stream>>>(
        cat3, 384, Hf0, row_start, deg, csr,
        Whi + 16384, Wlo + 16384, b_convs, cat3 + 128, 384, Hf1);
    gin_layer<true><<<layer_blocks, gblk, 0, stream>>>(
        cat3 + 128, 384, Hf1, row_start, deg, csr,
        Whi + 32768, Wlo + 32768, b_convs + 128, cat3 + 256, 384, Hf0);

    // --- fused layer 3 + output projection + softmax -> d_out ---
    gin_final<<<layer_blocks, gblk, 0, stream>>>(
        cat3, Hf0, row_start, deg, csr,
        Whi + 49152, Wlo + 49152, b_convs + 256,
        Whi + 65536, Wlo + 65536, b_out, out);
}

// Round 3
// 509.029 us; speedup vs baseline: 1.8950x; 1.0305x over previous
//
#include <hip/hip_runtime.h>
#include <hip/hip_bf16.h>
#include <hip/hip_fp16.h>

#define GN 100000
#define GE 600000
#define SCAN_NBLK 98   // ceil(GN / 1024)
#define ALD 132        // fp32 LDS leading dim: 128 + 4

typedef __bf16    bf16x8 __attribute__((ext_vector_type(8)));
typedef __bf16    bf16x4 __attribute__((ext_vector_type(4)));
typedef _Float16  f16x8  __attribute__((ext_vector_type(8)));
typedef float     f32x4  __attribute__((ext_vector_type(4)));

// ---------------------------------------------------------------------------
// Weight pre-conversion: fp32 -> (hi, lo) bf16 planes, ONCE per launch.
// [0,16384) W_in[128,128]; [16384,65536) W_convs[3][128][128];
// [65536,98304) W_out[64,512]. All row-major [OC, K].
// ---------------------------------------------------------------------------
__global__ __launch_bounds__(256) void convert_w(
    const float* __restrict__ Win, const float* __restrict__ Wc,
    const float* __restrict__ Wout,
    __bf16* __restrict__ hi, __bf16* __restrict__ lo)
{
    const int i = blockIdx.x * 256 + threadIdx.x;
    if (i >= 98304) return;
    float v;
    if (i < 16384)      v = Win[i];
    else if (i < 65536) v = Wc[i - 16384];
    else                v = Wout[i - 65536];
    const __bf16 h = (__bf16)v;
    hi[i] = h;
    lo[i] = (__bf16)(v - (float)h);
}

// ---------------------------------------------------------------------------
// Wide-issue 8-row fp16 gather. Indices are at CONSECUTIVE csr addresses, so
// one coalesced 64-lane load grabs up to 64 neighbor indices per row (lane l
// holds csr[start+l]); indices are then broadcast with __shfl and row-loads
// issued in chunks of 4 per row = 32 outstanding loads, ONE wait per chunk.
// Serial latency chain: 1 idx round-trip + ceil(maxd/4) chunk round-trips
// (vs maxd round-trips in the old per-neighbor walk). Outer window loop
// handles degree > 64. All speculative loads are clamp-protected.
// Ends with __syncthreads() + accumulate into Acc rows [wave*8, wave*8+8).
// ---------------------------------------------------------------------------
__device__ __forceinline__ void gather8_f16(
    const uint* __restrict__ Hw,
    const int* __restrict__ row_start,
    const int* __restrict__ deg,
    const int* __restrict__ csr,
    const int row0, const int wave, const int lane,
    float* __restrict__ Acc)
{
    float2 acc8[8];
    int start8[8], deg8[8];
    int maxd = 0;
#pragma unroll
    for (int r = 0; r < 8; ++r) {
        acc8[r] = make_float2(0.f, 0.f);
        const int v = row0 + wave * 8 + r;
        start8[r] = (v < GN) ? row_start[v] : 0;
        deg8[r]   = (v < GN) ? deg[v] : 0;
        maxd = max(maxd, deg8[r]);
    }

    for (int b = 0; b < maxd; b += 64) {
        // one coalesced load of up to 64 indices per row; lane l holds
        // csr[start + b + l], clamped so every lane has a VALID node id.
        int idx8[8];
#pragma unroll
        for (int r = 0; r < 8; ++r) {
            const int off = max(min(b + lane, deg8[r] - 1), 0);
            idx8[r] = min(max(csr[start8[r] + off], 0), GN - 1);
        }
        const int wend = min(maxd - b, 64);
        for (int c = 0; c < wend; c += 4) {
            uint t[8][4];
#pragma unroll
            for (int cc = 0; cc < 4; ++cc) {
#pragma unroll
                for (int r = 0; r < 8; ++r) {
                    const int s = __shfl(idx8[r], c + cc);
                    t[r][cc] = Hw[(size_t)s * 64 + lane];
                }
            }
#pragma unroll
            for (int cc = 0; cc < 4; ++cc) {
                const int k = b + c + cc;
#pragma unroll
                for (int r = 0; r < 8; ++r) {
                    const float m = (k < deg8[r]) ? 1.f : 0.f;
                    union { uint u; _Float16 h[2]; } cv;
                    cv.u = t[r][cc];
                    acc8[r].x = fmaf(m, (float)cv.h[0], acc8[r].x);
                    acc8[r].y = fmaf(m, (float)cv.h[1], acc8[r].y);
                }
            }
        }
    }

    __syncthreads();   // make Phase-A1 Acc writes visible before RMW
    const int j = lane * 2;
#pragma unroll
    for (int r = 0; r < 8; ++r) {
        float* a = &Acc[(wave * 8 + r) * ALD + j];
        a[0] += acc8[r].x;
        a[1] += acc8[r].y;
    }
}

// ---------------------------------------------------------------------------
// Fused GIN layer (layers 0..2 of the pipeline): C = (gather?) @ W^T + b.
// cat buffer is [GN,384] (blocks 0..2); layer 3 is fused into gin_final.
// ---------------------------------------------------------------------------
template<bool GATHER>
__global__ __launch_bounds__(512, 4) void gin_layer(
    const float* __restrict__ H, int ldH,      // fp32 self rows (cat block / x)
    const _Float16* __restrict__ HfIn,         // dense fp16 copy for gather
    const int* __restrict__ row_start,
    const int* __restrict__ deg,
    const int* __restrict__ csr,
    const __bf16* __restrict__ Whi,            // [128,128]
    const __bf16* __restrict__ Wlo,
    const float* __restrict__ bias,            // [128]
    float* __restrict__ C, int ldC,
    _Float16* __restrict__ HfOut)              // dense fp16 copy of C
{
    constexpr int K = 128;

    __shared__ float Acc[64 * ALD];      // 33792 B

    const int tid  = threadIdx.x;
    const int wave = tid >> 6;
    const int lane = tid & 63;
    const int row0 = blockIdx.x * 64;
    const int wm   = (wave >> 2) * 32;   // 0/32
    const int wn   = (wave & 3) * 32;    // 0/32/64/96
    const int quad = lane >> 4;
    const int l15  = lane & 15;

    // ---- Phase A1: Acc = self rows ----
#pragma unroll
    for (int p = 0; p < 4; ++p) {
        const int q  = tid + p * 512;
        const int r  = q >> 5;
        const int c4 = (q & 31) * 4;
        float4 v = make_float4(0.f, 0.f, 0.f, 0.f);
        if (row0 + r < GN) v = *(const float4*)(H + (size_t)(row0 + r) * ldH + c4);
        *(float4*)&Acc[r * ALD + c4] = v;
    }

    // ---- Phase A2 (GATHER): wide-issue 8-row fp16 gather ----
    if (GATHER)
        gather8_f16((const uint*)HfIn, row_start, deg, csr, row0, wave, lane, Acc);
    __syncthreads();

    // ---- Phase B: 3-term MFMA with in-register hi/lo split of A ----
    f32x4 acc[2][2];
#pragma unroll
    for (int i = 0; i < 2; ++i)
#pragma unroll
        for (int j = 0; j < 2; ++j) acc[i][j] = (f32x4)(0.0f);

#pragma unroll
    for (int ks = 0; ks < 4; ++ks) {
        const int kt = ks * 32 + quad * 8;
        bf16x8 ahi[2], alo[2];
#pragma unroll
        for (int mt = 0; mt < 2; ++mt) {
            const float* ap = &Acc[(wm + mt * 16 + l15) * ALD + kt];
            const f32x4 p = *(const f32x4*)ap;
            const f32x4 q = *(const f32x4*)(ap + 4);
#pragma unroll
            for (int e = 0; e < 4; ++e) {
                const __bf16 hp = (__bf16)p[e];
                const __bf16 hq = (__bf16)q[e];
                ahi[mt][e]     = hp;
                ahi[mt][e + 4] = hq;
                alo[mt][e]     = (__bf16)(p[e] - (float)hp);
                alo[mt][e + 4] = (__bf16)(q[e] - (float)hq);
            }
        }
        bf16x8 whi[2], wlo[2];
#pragma unroll
        for (int nt = 0; nt < 2; ++nt) {
            const int n = wn + nt * 16 + l15;
            whi[nt] = *(const bf16x8*)(Whi + (size_t)n * K + kt);
            wlo[nt] = *(const bf16x8*)(Wlo + (size_t)n * K + kt);
        }
#pragma unroll
        for (int mt = 0; mt < 2; ++mt)
#pragma unroll
            for (int nt = 0; nt < 2; ++nt) {
                acc[mt][nt] = __builtin_amdgcn_mfma_f32_16x16x32_bf16(
                    ahi[mt], whi[nt], acc[mt][nt], 0, 0, 0);
                acc[mt][nt] = __builtin_amdgcn_mfma_f32_16x16x32_bf16(
                    ahi[mt], wlo[nt], acc[mt][nt], 0, 0, 0);
                acc[mt][nt] = __builtin_amdgcn_mfma_f32_16x16x32_bf16(
                    alo[mt], whi[nt], acc[mt][nt], 0, 0, 0);
            }
    }
    __syncthreads();

    // ---- Phase C: epilogue via Acc, coalesced fp32 + fp16 stores ----
#pragma unroll
    for (int nt = 0; nt < 2; ++nt) {
        const int col = wn + nt * 16 + l15;
        const float b = bias[col];
#pragma unroll
        for (int mt = 0; mt < 2; ++mt)
#pragma unroll
            for (int r4 = 0; r4 < 4; ++r4)
                Acc[(wm + mt * 16 + quad * 4 + r4) * ALD + col] = acc[mt][nt][r4] + b;
    }
    __syncthreads();
#pragma unroll
    for (int p = 0; p < 4; ++p) {
        const int q  = tid + p * 512;
        const int r  = q >> 5;
        const int c4 = (q & 31) * 4;
        const int gr = row0 + r;
        if (gr < GN)
            *(float4*)(C + (size_t)gr * ldC + c4) = *(const float4*)&Acc[r * ALD + c4];
    }
#pragma unroll
    for (int p = 0; p < 2; ++p) {
        const int q = tid + p * 512;
        const int r = q >> 4;
        const int g = (q & 15) * 8;
        const int gr = row0 + r;
        if (gr < GN) {
            const float4 a = *(const float4*)&Acc[r * ALD + g];
            const float4 b = *(const float4*)&Acc[r * ALD + g + 4];
            f16x8 o = {(_Float16)a.x, (_Float16)a.y, (_Float16)a.z, (_Float16)a.w,
                       (_Float16)b.x, (_Float16)b.y, (_Float16)b.z, (_Float16)b.w};
            *(f16x8*)&HfOut[(size_t)gr * 128 + g] = o;
        }
    }
}

// ---------------------------------------------------------------------------
// Fused layer 3 + output projection + softmax.
// Cst ALIASES Acc (Cst is only live after all B2 reads of Acc complete,
// enforced by the extra __syncthreads() after the B2 MFMA loop).
// ---------------------------------------------------------------------------
__global__ __launch_bounds__(512, 4) void gin_final(
    const float* __restrict__ cat3,            // [GN,384]
    const _Float16* __restrict__ HfIn,         // h2 fp16
    const int* __restrict__ row_start,
    const int* __restrict__ deg,
    const int* __restrict__ csr,
    const __bf16* __restrict__ Whi3,           // Wc[2] planes [128,128]
    const __bf16* __restrict__ Wlo3,
    const float* __restrict__ b3,              // [128]
    const __bf16* __restrict__ WhiO,           // W_out planes [64,512]
    const __bf16* __restrict__ WloO,
    const float* __restrict__ bO,              // [64]
    float* __restrict__ out)                   // [GN,64]
{
    constexpr int CLD = 68;

    __shared__ float Smem[64 * ALD];     // 33792 B; Acc and Cst time-share it
    float* const Acc = Smem;
    float* const Cst = Smem;             // 64*CLD*4 = 17408 B <= 33792 B

    const int tid  = threadIdx.x;
    const int wave = tid >> 6;
    const int lane = tid & 63;
    const int row0 = blockIdx.x * 64;
    const int quad = lane >> 4;
    const int l15  = lane & 15;

    // ---- Phase A1: self rows = cat3 block 2 ----
#pragma unroll
    for (int p = 0; p < 4; ++p) {
        const int q  = tid + p * 512;
        const int r  = q >> 5;
        const int c4 = (q & 31) * 4;
        float4 v = make_float4(0.f, 0.f, 0.f, 0.f);
        if (row0 + r < GN)
            v = *(const float4*)(cat3 + (size_t)(row0 + r) * 384 + 256 + c4);
        *(float4*)&Acc[r * ALD + c4] = v;
    }

    // ---- Phase A2: wide-issue gather ----
    gather8_f16((const uint*)HfIn, row_start, deg, csr, row0, wave, lane, Acc);
    __syncthreads();

    // ---- Phase B1: GEMM1 (K=128) -> h3, 2m x 4n wave grid ----
    const int wm = (wave >> 2) * 32;
    const int wn = (wave & 3) * 32;
    f32x4 acc1[2][2];
#pragma unroll
    for (int i = 0; i < 2; ++i)
#pragma unroll
        for (int j = 0; j < 2; ++j) acc1[i][j] = (f32x4)(0.0f);

#pragma unroll
    for (int ks = 0; ks < 4; ++ks) {
        const int kt = ks * 32 + quad * 8;
        bf16x8 ahi[2], alo[2];
#pragma unroll
        for (int mt = 0; mt < 2; ++mt) {
            const float* ap = &Acc[(wm + mt * 16 + l15) * ALD + kt];
            const f32x4 p = *(const f32x4*)ap;
            const f32x4 q = *(const f32x4*)(ap + 4);
#pragma unroll
            for (int e = 0; e < 4; ++e) {
                const __bf16 hp = (__bf16)p[e];
                const __bf16 hq = (__bf16)q[e];
                ahi[mt][e]     = hp;
                ahi[mt][e + 4] = hq;
                alo[mt][e]     = (__bf16)(p[e] - (float)hp);
                alo[mt][e + 4] = (__bf16)(q[e] - (float)hq);
            }
        }
        bf16x8 whi[2], wlo[2];
#pragma unroll
        for (int nt = 0; nt < 2; ++nt) {
            const int n = wn + nt * 16 + l15;
            whi[nt] = *(const bf16x8*)(Whi3 + (size_t)n * 128 + kt);
            wlo[nt] = *(const bf16x8*)(Wlo3 + (size_t)n * 128 + kt);
        }
#pragma unroll
        for (int mt = 0; mt < 2; ++mt)
#pragma unroll
            for (int nt = 0; nt < 2; ++nt) {
                acc1[mt][nt] = __builtin_amdgcn_mfma_f32_16x16x32_bf16(
                    ahi[mt], whi[nt], acc1[mt][nt], 0, 0, 0);
                acc1[mt][nt] = __builtin_amdgcn_mfma_f32_16x16x32_bf16(
                    ahi[mt], wlo[nt], acc1[mt][nt], 0, 0, 0);
                acc1[mt][nt] = __builtin_amdgcn_mfma_f32_16x16x32_bf16(
                    alo[mt], whi[nt], acc1[mt][nt], 0, 0, 0);
            }
    }
    __syncthreads();

    // h3 + b3 -> Acc (overwrites gather input; all reads done)
#pragma unroll
    for (int nt = 0; nt < 2; ++nt) {
        const int col = wn + nt * 16 + l15;
        const float b = b3[col];
#pragma unroll
        for (int mt = 0; mt < 2; ++mt)
#pragma unroll
            for (int r4 = 0; r4 < 4; ++r4)
                Acc[(wm + mt * 16 + quad * 4 + r4) * ALD + col] = acc1[mt][nt][r4] + b;
    }
    __syncthreads();

    // ---- Phase B2: GEMM2 (K=512), 2m x 2n x 2k wave grid ----
    const int wk  = wave & 1;
    const int wn2 = ((wave >> 1) & 1) * 32;
    const int wm2 = ((wave >> 2) & 1) * 32;
    f32x4 acc2[2][2];
#pragma unroll
    for (int i = 0; i < 2; ++i)
#pragma unroll
        for (int j = 0; j < 2; ++j) acc2[i][j] = (f32x4)(0.0f);

#pragma unroll
    for (int ks = 0; ks < 8; ++ks) {
        const int kg = wk * 256 + ks * 32 + quad * 8;
        bf16x8 ahi[2], alo[2];
#pragma unroll
        for (int mt = 0; mt < 2; ++mt) {
            const int row = wm2 + mt * 16 + l15;
            f32x4 p, q;
            if (kg < 384) {
                // direct global fragment (rows past GN read safe in-ws bytes;
                // their outputs are never stored)
                const float* ap = cat3 + (size_t)(row0 + row) * 384 + kg;
                p = *(const f32x4*)ap;
                q = *(const f32x4*)(ap + 4);
            } else {
                const float* ap = &Acc[row * ALD + (kg - 384)];
                p = *(const f32x4*)ap;
                q = *(const f32x4*)(ap + 4);
            }
#pragma unroll
            for (int e = 0; e < 4; ++e) {
                const __bf16 hp = (__bf16)p[e];
                const __bf16 hq = (__bf16)q[e];
                ahi[mt][e]     = hp;
                ahi[mt][e + 4] = hq;
                alo[mt][e]     = (__bf16)(p[e] - (float)hp);
                alo[mt][e + 4] = (__bf16)(q[e] - (float)hq);
            }
        }
        bf16x8 whi[2], wlo[2];
#pragma unroll
        for (int nt = 0; nt < 2; ++nt) {
            const int n = wn2 + nt * 16 + l15;
            whi[nt] = *(const bf16x8*)(WhiO + (size_t)n * 512 + kg);
            wlo[nt] = *(const bf16x8*)(WloO + (size_t)n * 512 + kg);
        }
#pragma unroll
        for (int mt = 0; mt < 2; ++mt)
#pragma unroll
            for (int nt = 0; nt < 2; ++nt) {
                acc2[mt][nt] = __builtin_amdgcn_mfma_f32_16x16x32_bf16(
                    ahi[mt], whi[nt], acc2[mt][nt], 0, 0, 0);
                acc2[mt][nt] = __builtin_amdgcn_mfma_f32_16x16x32_bf16(
                    ahi[mt], wlo[nt], acc2[mt][nt], 0, 0, 0);
                acc2[mt][nt] = __builtin_amdgcn_mfma_f32_16x16x32_bf16(
                    alo[mt], whi[nt], acc2[mt][nt], 0, 0, 0);
            }
    }

    // All B2 reads of Acc must complete before Cst (alias of Acc) is written.
    __syncthreads();

    // ---- k-half reduction in Cst ----
    if (wk == 1) {
#pragma unroll
        for (int nt = 0; nt < 2; ++nt)
#pragma unroll
            for (int mt = 0; mt < 2; ++mt)
#pragma unroll
                for (int r4 = 0; r4 < 4; ++r4)
                    Cst[(wm2 + mt * 16 + quad * 4 + r4) * CLD + wn2 + nt * 16 + l15]
                        = acc2[mt][nt][r4];
    }
    __syncthreads();
    if (wk == 0) {
#pragma unroll
        for (int nt = 0; nt < 2; ++nt) {
            const int col = wn2 + nt * 16 + l15;
            const float b = bO[col];
#pragma unroll
            for (int mt = 0; mt < 2; ++mt)
#pragma unroll
                for (int r4 = 0; r4 < 4; ++r4) {
                    const int idx = (wm2 + mt * 16 + quad * 4 + r4) * CLD + col;
                    Cst[idx] = Cst[idx] + acc2[mt][nt][r4] + b;
                }
        }
    }
    __syncthreads();

    // ---- Phase C: softmax, one wave per row (8 rows/wave) ----
    for (int i = 0; i < 8; ++i) {
        const int r = wave * 8 + i;
        const float v = Cst[r * CLD + lane];
        float m = v;
#pragma unroll
        for (int off = 32; off > 0; off >>= 1) m = fmaxf(m, __shfl_xor(m, off));
        const float e = __expf(v - m);
        float s = e;
#pragma unroll
        for (int off = 32; off > 0; off >>= 1) s += __shfl_xor(s, off);
        const int gr = row0 + r;
        if (gr < GN) out[(size_t)gr * 64 + lane] = e / s;
    }
}

// ---------------------------------------------------------------------------
// CSR construction (graph static; built once per launch)
// ---------------------------------------------------------------------------
__global__ __launch_bounds__(256) void count_deg(const int* __restrict__ dst,
                                                 int* __restrict__ deg)
{
    const int e = blockIdx.x * 256 + threadIdx.x;
    if (e < GE) atomicAdd(&deg[dst[e]], 1);
}

__global__ __launch_bounds__(256) void scan_pass1(const int* __restrict__ deg,
                                                  int* __restrict__ excl,
                                                  int* __restrict__ blockSums)
{
    __shared__ int s[256];
    const int t = threadIdx.x;
    const int base = blockIdx.x * 1024 + t * 4;

    int4 v = make_int4(0, 0, 0, 0);
    if (base + 3 < GN) {
        v = *(const int4*)(deg + base);
    } else {
        if (base + 0 < GN) v.x = deg[base + 0];
        if (base + 1 < GN) v.y = deg[base + 1];
        if (base + 2 < GN) v.z = deg[base + 2];
        if (base + 3 < GN) v.w = deg[base + 3];
    }
    const int mysum = v.x + v.y + v.z + v.w;
    s[t] = mysum;
    __syncthreads();
    for (int off = 1; off < 256; off <<= 1) {
        const int val = (t >= off) ? s[t - off] : 0;
        __syncthreads();
        s[t] += val;
        __syncthreads();
    }
    int4 o;
    o.x = s[t] - mysum;
    o.y = o.x + v.x;
    o.z = o.y + v.y;
    o.w = o.z + v.z;
    if (base + 3 < GN) {
        *(int4*)(excl + base) = o;
    } else {
        if (base + 0 < GN) excl[base + 0] = o.x;
        if (base + 1 < GN) excl[base + 1] = o.y;
        if (base + 2 < GN) excl[base + 2] = o.z;
        if (base + 3 < GN) excl[base + 3] = o.w;
    }
    if (t == 255) blockSums[blockIdx.x] = s[255];
}

__global__ __launch_bounds__(128) void scan_pass2(const int* __restrict__ blockSums,
                                                  int* __restrict__ blockOffs, int n)
{
    __shared__ int s[128];
    const int t = threadIdx.x;
    const int v = (t < n) ? blockSums[t] : 0;
    s[t] = v;
    __syncthreads();
    for (int off = 1; off < 128; off <<= 1) {
        const int val = (t >= off) ? s[t - off] : 0;
        __syncthreads();
        s[t] += val;
        __syncthreads();
    }
    if (t < n) blockOffs[t] = s[t] - v;
}

__global__ __launch_bounds__(256) void scan_pass3(int* __restrict__ excl,
                                                  const int* __restrict__ blockOffs,
                                                  int* __restrict__ cursor)
{
    const int i = blockIdx.x * 256 + threadIdx.x;
    if (i >= GN) return;
    const int v = excl[i] + blockOffs[i >> 10];
    excl[i]   = v;
    cursor[i] = v;
}

__global__ __launch_bounds__(256) void fill_csr(const int* __restrict__ src,
                                                const int* __restrict__ dst,
                                                int* __restrict__ cursor,
                                                int* __restrict__ csr)
{
    const int e = blockIdx.x * 256 + threadIdx.x;
    if (e >= GE) return;
    const int pos = atomicAdd(&cursor[dst[e]], 1);
    csr[pos] = src[e];
}

extern "C" void kernel_launch(void* const* d_in, const int* in_sizes, int n_in,
                              void* d_out, int out_size, void* d_ws, size_t ws_size,
                              hipStream_t stream)
{
    const float* x       = (const float*)d_in[0];
    const int*   src     = (const int*)d_in[1];            // edge_index[0]
    const int*   dst     = ((const int*)d_in[1]) + GE;     // edge_index[1]
    const float* W_in    = (const float*)d_in[2];
    const float* b_in    = (const float*)d_in[3];
    const float* W_convs = (const float*)d_in[4];          // [3,128,128]
    const float* b_convs = (const float*)d_in[5];          // [3,128]
    const float* W_out   = (const float*)d_in[6];          // [64,512]
    const float* b_out   = (const float*)d_in[7];
    float*       out     = (float*)d_out;                  // [GN,64]

    // d_ws layout (~209 MB of the >=256 MB workspace):
    //   cat3 [GN,384] fp32 | Hf0 | Hf1 (fp16 [GN,128] each) | CSR scratch |
    //   hi/lo weight planes (98304 bf16 each).  d_out holds ONLY the output.
    float*    cat3 = (float*)d_ws;
    _Float16* Hf0  = (_Float16*)(cat3 + (size_t)GN * 384);
    _Float16* Hf1  = Hf0 + (size_t)GN * 128;
    int*      deg       = (int*)(Hf1 + (size_t)GN * 128);
    int*      row_start = deg + GN;
    int*      cursor    = row_start + GN;
    int*      blockSums = cursor + GN;
    int*      blockOffs = blockSums + 128;
    int*      csr       = blockOffs + 128;
    __bf16*   Whi       = (__bf16*)(csr + GE);   // 98304 bf16
    __bf16*   Wlo       = Whi + 98304;

    const dim3 blk(256);
    const dim3 gblk(512);
    const int edge_blocks  = (GE + 255) / 256;
    const int node_blocks  = (GN + 255) / 256;
    const int layer_blocks = (GN + 63) / 64;     // 1563

    // --- CSR build ---
    hipMemsetAsync(deg, 0, GN * sizeof(int), stream);
    count_deg<<<edge_blocks, blk, 0, stream>>>(dst, deg);
    scan_pass1<<<SCAN_NBLK, blk, 0, stream>>>(deg, row_start, blockSums);
    scan_pass2<<<1, 128, 0, stream>>>(blockSums, blockOffs, SCAN_NBLK);
    scan_pass3<<<node_blocks, blk, 0, stream>>>(row_start, blockOffs, cursor);
    fill_csr<<<edge_blocks, blk, 0, stream>>>(src, dst, cursor, csr);

    // --- weight pre-conversion (all hi/lo planes incl. W_out) ---
    convert_w<<<(98304 + 255) / 256, blk, 0, stream>>>(W_in, W_convs, W_out, Whi, Wlo);

    // --- input projection -> cat3 block 0 + Hf0 ---
    gin_layer<false><<<layer_blocks, gblk, 0, stream>>>(
        x, 128, nullptr, nullptr, nullptr, nullptr,
        Whi, Wlo, b_in, cat3, 384, Hf0);

    // --- layers 1..2: fp16 gather (ping-pong Hf) + linear ---
    gin_layer<true><<<layer_blocks, gblk, 0, stream>>>(
        cat3, 384, Hf0, row_start, deg, csr,
        Whi + 16384, Wlo + 16384, b_convs, cat3 + 128, 384, Hf1);
    gin_layer<true><<<layer_blocks, gblk, 0, stream>>>(
        cat3 + 128, 384, Hf1, row_start, deg, csr,
        Whi + 32768, Wlo + 32768, b_convs + 128, cat3 + 256, 384, Hf0);

    // --- fused layer 3 + output projection + softmax -> d_out ---
    gin_final<<<layer_blocks, gblk, 0, stream>>>(
        cat3, Hf0, row_start, deg, csr,
        Whi + 49152, Wlo + 49152, b_convs + 256,
        Whi + 65536, Wlo + 65536, b_out, out);
}

// Round 4
// 464.886 us; speedup vs baseline: 2.0749x; 1.0950x over previous
//
#include <hip/hip_runtime.h>
#include <hip/hip_bf16.h>
#include <hip/hip_fp16.h>

#define GN 100000
#define GE 600000
#define SCAN_NBLK 98   // ceil(GN / 1024)
#define ALD 132        // fp32 LDS leading dim: 128 + 4

typedef __bf16    bf16x8 __attribute__((ext_vector_type(8)));
typedef __bf16    bf16x4 __attribute__((ext_vector_type(4)));
typedef _Float16  f16x8  __attribute__((ext_vector_type(8)));
typedef float     f32x4  __attribute__((ext_vector_type(4)));

// ---------------------------------------------------------------------------
// Weight pre-conversion: fp32 -> (hi, lo) bf16 planes, ONCE per launch.
// [0,16384) W_in[128,128]; [16384,65536) W_convs[3][128][128];
// [65536,98304) W_out[64,512]. All row-major [OC, K].
// ---------------------------------------------------------------------------
__global__ __launch_bounds__(256) void convert_w(
    const float* __restrict__ Win, const float* __restrict__ Wc,
    const float* __restrict__ Wout,
    __bf16* __restrict__ hi, __bf16* __restrict__ lo)
{
    const int i = blockIdx.x * 256 + threadIdx.x;
    if (i >= 98304) return;
    float v;
    if (i < 16384)      v = Win[i];
    else if (i < 65536) v = Wc[i - 16384];
    else                v = Wout[i - 65536];
    const __bf16 h = (__bf16)v;
    hi[i] = h;
    lo[i] = (__bf16)(v - (float)h);
}

// ---------------------------------------------------------------------------
// Wide-issue 8-row fp16 gather (one wave owns 8 rows). One coalesced 64-lane
// load grabs up to 64 neighbor indices per row; indices broadcast via __shfl;
// row-loads issued in chunks of 4 per row = 32 outstanding, one wait/chunk.
// Ends with __syncthreads() + accumulate into Acc rows [wave*8, wave*8+8).
// ---------------------------------------------------------------------------
__device__ __forceinline__ void gather8_f16(
    const uint* __restrict__ Hw,
    const int* __restrict__ row_start,
    const int* __restrict__ deg,
    const int* __restrict__ csr,
    const int row0, const int wave, const int lane,
    float* __restrict__ Acc)
{
    float2 acc8[8];
    int start8[8], deg8[8];
    int maxd = 0;
#pragma unroll
    for (int r = 0; r < 8; ++r) {
        acc8[r] = make_float2(0.f, 0.f);
        const int v = row0 + wave * 8 + r;
        start8[r] = (v < GN) ? row_start[v] : 0;
        deg8[r]   = (v < GN) ? deg[v] : 0;
        maxd = max(maxd, deg8[r]);
    }

    for (int b = 0; b < maxd; b += 64) {
        int idx8[8];
#pragma unroll
        for (int r = 0; r < 8; ++r) {
            const int off = max(min(b + lane, deg8[r] - 1), 0);
            idx8[r] = min(max(csr[start8[r] + off], 0), GN - 1);
        }
        const int wend = min(maxd - b, 64);
        for (int c = 0; c < wend; c += 4) {
            uint t[8][4];
#pragma unroll
            for (int cc = 0; cc < 4; ++cc) {
#pragma unroll
                for (int r = 0; r < 8; ++r) {
                    const int s = __shfl(idx8[r], c + cc);
                    t[r][cc] = Hw[(size_t)s * 64 + lane];
                }
            }
#pragma unroll
            for (int cc = 0; cc < 4; ++cc) {
                const int k = b + c + cc;
#pragma unroll
                for (int r = 0; r < 8; ++r) {
                    const float m = (k < deg8[r]) ? 1.f : 0.f;
                    union { uint u; _Float16 h[2]; } cv;
                    cv.u = t[r][cc];
                    acc8[r].x = fmaf(m, (float)cv.h[0], acc8[r].x);
                    acc8[r].y = fmaf(m, (float)cv.h[1], acc8[r].y);
                }
            }
        }
    }

    __syncthreads();   // make Phase-A1 Acc writes visible before RMW
    const int j = lane * 2;
#pragma unroll
    for (int r = 0; r < 8; ++r) {
        float* a = &Acc[(wave * 8 + r) * ALD + j];
        a[0] += acc8[r].x;
        a[1] += acc8[r].y;
    }
}

// ---------------------------------------------------------------------------
// Fused GIN layer, 32-row tile / 256 threads (4 waves). Same per-wave work
// as the 64-row variant, but 2x the independent blocks (8/CU by LDS+waves)
// and 4-wave barriers instead of 8 -> more phase diversity per CU.
// ---------------------------------------------------------------------------
template<bool GATHER>
__global__ __launch_bounds__(256, 4) void gin_layer(
    const float* __restrict__ H, int ldH,      // fp32 self rows (cat block / x)
    const _Float16* __restrict__ HfIn,         // dense fp16 copy for gather
    const int* __restrict__ row_start,
    const int* __restrict__ deg,
    const int* __restrict__ csr,
    const __bf16* __restrict__ Whi,            // [128,128]
    const __bf16* __restrict__ Wlo,
    const float* __restrict__ bias,            // [128]
    float* __restrict__ C, int ldC,
    _Float16* __restrict__ HfOut)              // dense fp16 copy of C
{
    constexpr int K = 128;

    __shared__ float Acc[32 * ALD];      // 16896 B

    const int tid  = threadIdx.x;
    const int wave = tid >> 6;           // 0..3
    const int lane = tid & 63;
    const int row0 = blockIdx.x * 32;
    const int wn   = wave * 32;          // 0/32/64/96
    const int quad = lane >> 4;
    const int l15  = lane & 15;

    // ---- Phase A1: Acc = self rows (32 x 128 fp32) ----
#pragma unroll
    for (int p = 0; p < 4; ++p) {
        const int q  = tid + p * 256;
        const int r  = q >> 5;           // 0..31
        const int c4 = (q & 31) * 4;
        float4 v = make_float4(0.f, 0.f, 0.f, 0.f);
        if (row0 + r < GN) v = *(const float4*)(H + (size_t)(row0 + r) * ldH + c4);
        *(float4*)&Acc[r * ALD + c4] = v;
    }

    // ---- Phase A2 (GATHER): 4 waves x 8 rows ----
    if (GATHER)
        gather8_f16((const uint*)HfIn, row_start, deg, csr, row0, wave, lane, Acc);
    __syncthreads();

    // ---- Phase B: 3-term MFMA with in-register hi/lo split of A ----
    f32x4 acc[2][2];
#pragma unroll
    for (int i = 0; i < 2; ++i)
#pragma unroll
        for (int j = 0; j < 2; ++j) acc[i][j] = (f32x4)(0.0f);

#pragma unroll
    for (int ks = 0; ks < 4; ++ks) {
        const int kt = ks * 32 + quad * 8;
        bf16x8 ahi[2], alo[2];
#pragma unroll
        for (int mt = 0; mt < 2; ++mt) {
            const float* ap = &Acc[(mt * 16 + l15) * ALD + kt];
            const f32x4 p = *(const f32x4*)ap;
            const f32x4 q = *(const f32x4*)(ap + 4);
#pragma unroll
            for (int e = 0; e < 4; ++e) {
                const __bf16 hp = (__bf16)p[e];
                const __bf16 hq = (__bf16)q[e];
                ahi[mt][e]     = hp;
                ahi[mt][e + 4] = hq;
                alo[mt][e]     = (__bf16)(p[e] - (float)hp);
                alo[mt][e + 4] = (__bf16)(q[e] - (float)hq);
            }
        }
        bf16x8 whi[2], wlo[2];
#pragma unroll
        for (int nt = 0; nt < 2; ++nt) {
            const int n = wn + nt * 16 + l15;
            whi[nt] = *(const bf16x8*)(Whi + (size_t)n * K + kt);
            wlo[nt] = *(const bf16x8*)(Wlo + (size_t)n * K + kt);
        }
#pragma unroll
        for (int mt = 0; mt < 2; ++mt)
#pragma unroll
            for (int nt = 0; nt < 2; ++nt) {
                acc[mt][nt] = __builtin_amdgcn_mfma_f32_16x16x32_bf16(
                    ahi[mt], whi[nt], acc[mt][nt], 0, 0, 0);
                acc[mt][nt] = __builtin_amdgcn_mfma_f32_16x16x32_bf16(
                    ahi[mt], wlo[nt], acc[mt][nt], 0, 0, 0);
                acc[mt][nt] = __builtin_amdgcn_mfma_f32_16x16x32_bf16(
                    alo[mt], whi[nt], acc[mt][nt], 0, 0, 0);
            }
    }
    __syncthreads();

    // ---- Phase C: epilogue via Acc, coalesced fp32 + fp16 stores ----
#pragma unroll
    for (int nt = 0; nt < 2; ++nt) {
        const int col = wn + nt * 16 + l15;
        const float b = bias[col];
#pragma unroll
        for (int mt = 0; mt < 2; ++mt)
#pragma unroll
            for (int r4 = 0; r4 < 4; ++r4)
                Acc[(mt * 16 + quad * 4 + r4) * ALD + col] = acc[mt][nt][r4] + b;
    }
    __syncthreads();
#pragma unroll
    for (int p = 0; p < 4; ++p) {
        const int q  = tid + p * 256;
        const int r  = q >> 5;
        const int c4 = (q & 31) * 4;
        const int gr = row0 + r;
        if (gr < GN)
            *(float4*)(C + (size_t)gr * ldC + c4) = *(const float4*)&Acc[r * ALD + c4];
    }
#pragma unroll
    for (int p = 0; p < 2; ++p) {
        const int q = tid + p * 256;
        const int r = q >> 4;            // 0..31
        const int g = (q & 15) * 8;
        const int gr = row0 + r;
        if (gr < GN) {
            const float4 a = *(const float4*)&Acc[r * ALD + g];
            const float4 b = *(const float4*)&Acc[r * ALD + g + 4];
            f16x8 o = {(_Float16)a.x, (_Float16)a.y, (_Float16)a.z, (_Float16)a.w,
                       (_Float16)b.x, (_Float16)b.y, (_Float16)b.z, (_Float16)b.w};
            *(f16x8*)&HfOut[(size_t)gr * 128 + g] = o;
        }
    }
}

// ---------------------------------------------------------------------------
// Fused layer 3 + output projection + softmax, 32-row tile / 256 threads.
// Cst ALIASES Acc (Cst only live after all B2 reads of Acc, enforced by the
// extra __syncthreads() after the B2 MFMA loop). LDS 16896 B.
// ---------------------------------------------------------------------------
__global__ __launch_bounds__(256, 4) void gin_final(
    const float* __restrict__ cat3,            // [GN,384]
    const _Float16* __restrict__ HfIn,         // h2 fp16
    const int* __restrict__ row_start,
    const int* __restrict__ deg,
    const int* __restrict__ csr,
    const __bf16* __restrict__ Whi3,           // Wc[2] planes [128,128]
    const __bf16* __restrict__ Wlo3,
    const float* __restrict__ b3,              // [128]
    const __bf16* __restrict__ WhiO,           // W_out planes [64,512]
    const __bf16* __restrict__ WloO,
    const float* __restrict__ bO,              // [64]
    float* __restrict__ out)                   // [GN,64]
{
    constexpr int CLD = 68;

    __shared__ float Smem[32 * ALD];     // 16896 B; Acc and Cst time-share it
    float* const Acc = Smem;
    float* const Cst = Smem;             // 32*CLD*4 = 8704 B <= 16896 B

    const int tid  = threadIdx.x;
    const int wave = tid >> 6;           // 0..3
    const int lane = tid & 63;
    const int row0 = blockIdx.x * 32;
    const int quad = lane >> 4;
    const int l15  = lane & 15;

    // ---- Phase A1: self rows = cat3 block 2 (32 x 128) ----
#pragma unroll
    for (int p = 0; p < 4; ++p) {
        const int q  = tid + p * 256;
        const int r  = q >> 5;
        const int c4 = (q & 31) * 4;
        float4 v = make_float4(0.f, 0.f, 0.f, 0.f);
        if (row0 + r < GN)
            v = *(const float4*)(cat3 + (size_t)(row0 + r) * 384 + 256 + c4);
        *(float4*)&Acc[r * ALD + c4] = v;
    }

    // ---- Phase A2: wide-issue gather, 4 waves x 8 rows ----
    gather8_f16((const uint*)HfIn, row_start, deg, csr, row0, wave, lane, Acc);
    __syncthreads();

    // ---- Phase B1: GEMM1 (K=128) -> h3, 1m x 4n wave grid ----
    const int wn = wave * 32;
    f32x4 acc1[2][2];
#pragma unroll
    for (int i = 0; i < 2; ++i)
#pragma unroll
        for (int j = 0; j < 2; ++j) acc1[i][j] = (f32x4)(0.0f);

#pragma unroll
    for (int ks = 0; ks < 4; ++ks) {
        const int kt = ks * 32 + quad * 8;
        bf16x8 ahi[2], alo[2];
#pragma unroll
        for (int mt = 0; mt < 2; ++mt) {
            const float* ap = &Acc[(mt * 16 + l15) * ALD + kt];
            const f32x4 p = *(const f32x4*)ap;
            const f32x4 q = *(const f32x4*)(ap + 4);
#pragma unroll
            for (int e = 0; e < 4; ++e) {
                const __bf16 hp = (__bf16)p[e];
                const __bf16 hq = (__bf16)q[e];
                ahi[mt][e]     = hp;
                ahi[mt][e + 4] = hq;
                alo[mt][e]     = (__bf16)(p[e] - (float)hp);
                alo[mt][e + 4] = (__bf16)(q[e] - (float)hq);
            }
        }
        bf16x8 whi[2], wlo[2];
#pragma unroll
        for (int nt = 0; nt < 2; ++nt) {
            const int n = wn + nt * 16 + l15;
            whi[nt] = *(const bf16x8*)(Whi3 + (size_t)n * 128 + kt);
            wlo[nt] = *(const bf16x8*)(Wlo3 + (size_t)n * 128 + kt);
        }
#pragma unroll
        for (int mt = 0; mt < 2; ++mt)
#pragma unroll
            for (int nt = 0; nt < 2; ++nt) {
                acc1[mt][nt] = __builtin_amdgcn_mfma_f32_16x16x32_bf16(
                    ahi[mt], whi[nt], acc1[mt][nt], 0, 0, 0);
                acc1[mt][nt] = __builtin_amdgcn_mfma_f32_16x16x32_bf16(
                    ahi[mt], wlo[nt], acc1[mt][nt], 0, 0, 0);
                acc1[mt][nt] = __builtin_amdgcn_mfma_f32_16x16x32_bf16(
                    alo[mt], whi[nt], acc1[mt][nt], 0, 0, 0);
            }
    }
    __syncthreads();

    // h3 + b3 -> Acc (overwrites gather input; all reads done)
#pragma unroll
    for (int nt = 0; nt < 2; ++nt) {
        const int col = wn + nt * 16 + l15;
        const float b = b3[col];
#pragma unroll
        for (int mt = 0; mt < 2; ++mt)
#pragma unroll
            for (int r4 = 0; r4 < 4; ++r4)
                Acc[(mt * 16 + quad * 4 + r4) * ALD + col] = acc1[mt][nt][r4] + b;
    }
    __syncthreads();

    // ---- Phase B2: GEMM2 (K=512), 1m x 2n x 2k wave grid ----
    const int wk  = wave & 1;
    const int wn2 = (wave >> 1) * 32;    // 0/32
    f32x4 acc2[2][2];
#pragma unroll
    for (int i = 0; i < 2; ++i)
#pragma unroll
        for (int j = 0; j < 2; ++j) acc2[i][j] = (f32x4)(0.0f);

#pragma unroll
    for (int ks = 0; ks < 8; ++ks) {
        const int kg = wk * 256 + ks * 32 + quad * 8;
        bf16x8 ahi[2], alo[2];
#pragma unroll
        for (int mt = 0; mt < 2; ++mt) {
            const int row = mt * 16 + l15;   // 0..31
            f32x4 p, q;
            if (kg < 384) {
                const float* ap = cat3 + (size_t)(row0 + row) * 384 + kg;
                p = *(const f32x4*)ap;
                q = *(const f32x4*)(ap + 4);
            } else {
                const float* ap = &Acc[row * ALD + (kg - 384)];
                p = *(const f32x4*)ap;
                q = *(const f32x4*)(ap + 4);
            }
#pragma unroll
            for (int e = 0; e < 4; ++e) {
                const __bf16 hp = (__bf16)p[e];
                const __bf16 hq = (__bf16)q[e];
                ahi[mt][e]     = hp;
                ahi[mt][e + 4] = hq;
                alo[mt][e]     = (__bf16)(p[e] - (float)hp);
                alo[mt][e + 4] = (__bf16)(q[e] - (float)hq);
            }
        }
        bf16x8 whi[2], wlo[2];
#pragma unroll
        for (int nt = 0; nt < 2; ++nt) {
            const int n = wn2 + nt * 16 + l15;
            whi[nt] = *(const bf16x8*)(WhiO + (size_t)n * 512 + kg);
            wlo[nt] = *(const bf16x8*)(WloO + (size_t)n * 512 + kg);
        }
#pragma unroll
        for (int mt = 0; mt < 2; ++mt)
#pragma unroll
            for (int nt = 0; nt < 2; ++nt) {
                acc2[mt][nt] = __builtin_amdgcn_mfma_f32_16x16x32_bf16(
                    ahi[mt], whi[nt], acc2[mt][nt], 0, 0, 0);
                acc2[mt][nt] = __builtin_amdgcn_mfma_f32_16x16x32_bf16(
                    ahi[mt], wlo[nt], acc2[mt][nt], 0, 0, 0);
                acc2[mt][nt] = __builtin_amdgcn_mfma_f32_16x16x32_bf16(
                    alo[mt], whi[nt], acc2[mt][nt], 0, 0, 0);
            }
    }

    // All B2 reads of Acc must complete before Cst (alias of Acc) is written.
    __syncthreads();

    // ---- k-half reduction in Cst ----
    if (wk == 1) {
#pragma unroll
        for (int nt = 0; nt < 2; ++nt)
#pragma unroll
            for (int mt = 0; mt < 2; ++mt)
#pragma unroll
                for (int r4 = 0; r4 < 4; ++r4)
                    Cst[(mt * 16 + quad * 4 + r4) * CLD + wn2 + nt * 16 + l15]
                        = acc2[mt][nt][r4];
    }
    __syncthreads();
    if (wk == 0) {
#pragma unroll
        for (int nt = 0; nt < 2; ++nt) {
            const int col = wn2 + nt * 16 + l15;
            const float b = bO[col];
#pragma unroll
            for (int mt = 0; mt < 2; ++mt)
#pragma unroll
                for (int r4 = 0; r4 < 4; ++r4) {
                    const int idx = (mt * 16 + quad * 4 + r4) * CLD + col;
                    Cst[idx] = Cst[idx] + acc2[mt][nt][r4] + b;
                }
        }
    }
    __syncthreads();

    // ---- Phase C: softmax, 4 waves x 8 rows ----
    for (int i = 0; i < 8; ++i) {
        const int r = wave * 8 + i;      // 0..31
        const float v = Cst[r * CLD + lane];
        float m = v;
#pragma unroll
        for (int off = 32; off > 0; off >>= 1) m = fmaxf(m, __shfl_xor(m, off));
        const float e = __expf(v - m);
        float s = e;
#pragma unroll
        for (int off = 32; off > 0; off >>= 1) s += __shfl_xor(s, off);
        const int gr = row0 + r;
        if (gr < GN) out[(size_t)gr * 64 + lane] = e / s;
    }
}

// ---------------------------------------------------------------------------
// CSR construction (graph static; built once per launch)
// ---------------------------------------------------------------------------
__global__ __launch_bounds__(256) void count_deg(const int* __restrict__ dst,
                                                 int* __restrict__ deg)
{
    const int e = blockIdx.x * 256 + threadIdx.x;
    if (e < GE) atomicAdd(&deg[dst[e]], 1);
}

__global__ __launch_bounds__(256) void scan_pass1(const int* __restrict__ deg,
                                                  int* __restrict__ excl,
                                                  int* __restrict__ blockSums)
{
    __shared__ int s[256];
    const int t = threadIdx.x;
    const int base = blockIdx.x * 1024 + t * 4;

    int4 v = make_int4(0, 0, 0, 0);
    if (base + 3 < GN) {
        v = *(const int4*)(deg + base);
    } else {
        if (base + 0 < GN) v.x = deg[base + 0];
        if (base + 1 < GN) v.y = deg[base + 1];
        if (base + 2 < GN) v.z = deg[base + 2];
        if (base + 3 < GN) v.w = deg[base + 3];
    }
    const int mysum = v.x + v.y + v.z + v.w;
    s[t] = mysum;
    __syncthreads();
    for (int off = 1; off < 256; off <<= 1) {
        const int val = (t >= off) ? s[t - off] : 0;
        __syncthreads();
        s[t] += val;
        __syncthreads();
    }
    int4 o;
    o.x = s[t] - mysum;
    o.y = o.x + v.x;
    o.z = o.y + v.y;
    o.w = o.z + v.z;
    if (base + 3 < GN) {
        *(int4*)(excl + base) = o;
    } else {
        if (base + 0 < GN) excl[base + 0] = o.x;
        if (base + 1 < GN) excl[base + 1] = o.y;
        if (base + 2 < GN) excl[base + 2] = o.z;
        if (base + 3 < GN) excl[base + 3] = o.w;
    }
    if (t == 255) blockSums[blockIdx.x] = s[255];
}

__global__ __launch_bounds__(128) void scan_pass2(const int* __restrict__ blockSums,
                                                  int* __restrict__ blockOffs, int n)
{
    __shared__ int s[128];
    const int t = threadIdx.x;
    const int v = (t < n) ? blockSums[t] : 0;
    s[t] = v;
    __syncthreads();
    for (int off = 1; off < 128; off <<= 1) {
        const int val = (t >= off) ? s[t - off] : 0;
        __syncthreads();
        s[t] += val;
        __syncthreads();
    }
    if (t < n) blockOffs[t] = s[t] - v;
}

__global__ __launch_bounds__(256) void scan_pass3(int* __restrict__ excl,
                                                  const int* __restrict__ blockOffs,
                                                  int* __restrict__ cursor)
{
    const int i = blockIdx.x * 256 + threadIdx.x;
    if (i >= GN) return;
    const int v = excl[i] + blockOffs[i >> 10];
    excl[i]   = v;
    cursor[i] = v;
}

__global__ __launch_bounds__(256) void fill_csr(const int* __restrict__ src,
                                                const int* __restrict__ dst,
                                                int* __restrict__ cursor,
                                                int* __restrict__ csr)
{
    const int e = blockIdx.x * 256 + threadIdx.x;
    if (e >= GE) return;
    const int pos = atomicAdd(&cursor[dst[e]], 1);
    csr[pos] = src[e];
}

extern "C" void kernel_launch(void* const* d_in, const int* in_sizes, int n_in,
                              void* d_out, int out_size, void* d_ws, size_t ws_size,
                              hipStream_t stream)
{
    const float* x       = (const float*)d_in[0];
    const int*   src     = (const int*)d_in[1];            // edge_index[0]
    const int*   dst     = ((const int*)d_in[1]) + GE;     // edge_index[1]
    const float* W_in    = (const float*)d_in[2];
    const float* b_in    = (const float*)d_in[3];
    const float* W_convs = (const float*)d_in[4];          // [3,128,128]
    const float* b_convs = (const float*)d_in[5];          // [3,128]
    const float* W_out   = (const float*)d_in[6];          // [64,512]
    const float* b_out   = (const float*)d_in[7];
    float*       out     = (float*)d_out;                  // [GN,64]

    // d_ws layout (~209 MB of the >=256 MB workspace):
    //   cat3 [GN,384] fp32 | Hf0 | Hf1 (fp16 [GN,128] each) | CSR scratch |
    //   hi/lo weight planes (98304 bf16 each).  d_out holds ONLY the output.
    float*    cat3 = (float*)d_ws;
    _Float16* Hf0  = (_Float16*)(cat3 + (size_t)GN * 384);
    _Float16* Hf1  = Hf0 + (size_t)GN * 128;
    int*      deg       = (int*)(Hf1 + (size_t)GN * 128);
    int*      row_start = deg + GN;
    int*      cursor    = row_start + GN;
    int*      blockSums = cursor + GN;
    int*      blockOffs = blockSums + 128;
    int*      csr       = blockOffs + 128;
    __bf16*   Whi       = (__bf16*)(csr + GE);   // 98304 bf16
    __bf16*   Wlo       = Whi + 98304;

    const dim3 blk(256);
    const dim3 gblk(256);
    const int edge_blocks  = (GE + 255) / 256;
    const int node_blocks  = (GN + 255) / 256;
    const int layer_blocks = (GN + 31) / 32;     // 3125 (exact)

    // --- CSR build ---
    hipMemsetAsync(deg, 0, GN * sizeof(int), stream);
    count_deg<<<edge_blocks, blk, 0, stream>>>(dst, deg);
    scan_pass1<<<SCAN_NBLK, blk, 0, stream>>>(deg, row_start, blockSums);
    scan_pass2<<<1, 128, 0, stream>>>(blockSums, blockOffs, SCAN_NBLK);
    scan_pass3<<<node_blocks, blk, 0, stream>>>(row_start, blockOffs, cursor);
    fill_csr<<<edge_blocks, blk, 0, stream>>>(src, dst, cursor, csr);

    // --- weight pre-conversion (all hi/lo planes incl. W_out) ---
    convert_w<<<(98304 + 255) / 256, blk, 0, stream>>>(W_in, W_convs, W_out, Whi, Wlo);

    // --- input projection -> cat3 block 0 + Hf0 ---
    gin_layer<false><<<layer_blocks, gblk, 0, stream>>>(
        x, 128, nullptr, nullptr, nullptr, nullptr,
        Whi, Wlo, b_in, cat3, 384, Hf0);

    // --- layers 1..2: fp16 gather (ping-pong Hf) + linear ---
    gin_layer<true><<<layer_blocks, gblk, 0, stream>>>(
        cat3, 384, Hf0, row_start, deg, csr,
        Whi + 16384, Wlo + 16384, b_convs, cat3 + 128, 384, Hf1);
    gin_layer<true><<<layer_blocks, gblk, 0, stream>>>(
        cat3 + 128, 384, Hf1, row_start, deg, csr,
        Whi + 32768, Wlo + 32768, b_convs + 128, cat3 + 256, 384, Hf0);

    // --- fused layer 3 + output projection + softmax -> d_out ---
    gin_final<<<layer_blocks, gblk, 0, stream>>>(
        cat3, Hf0, row_start, deg, csr,
        Whi + 49152, Wlo + 49152, b_convs + 256,
        Whi + 65536, Wlo + 65536, b_out, out);
}